// Round 28
// baseline (323.984 us; speedup 1.0000x reference)
//
#include <hip/hip_runtime.h>
#include <math.h>

#define NGRID 8192

typedef unsigned short u16;
typedef _Float16 f16;
typedef __attribute__((ext_vector_type(4))) float f32x4;
typedef __attribute__((ext_vector_type(4))) _Float16 f16x4;
typedef __attribute__((ext_vector_type(8))) short bf16x8;
typedef __attribute__((ext_vector_type(4))) short sh4;

// fast gelu: Abramowitz-Stegun 7.1.26 erf, |abs err| <= 1.5e-7
__device__ __forceinline__ float gelu_f(float x){
    float z = fabsf(x) * 0.70710678118654752f;
    float t = __builtin_amdgcn_rcpf(fmaf(0.3275911f, z, 1.0f));
    float p = fmaf(fmaf(fmaf(fmaf(1.061405429f, t, -1.453152027f), t,
                1.421413741f), t, -0.284496736f), t, 0.254829592f) * t;
    float er = 1.0f - p * __expf(-z*z);
    float s = (x >= 0.0f) ? er : -er;
    return 0.5f * x * (1.0f + s);
}

__device__ __forceinline__ u16 bf16_of(float x){
    union { float f; unsigned u; } v; v.f = x;
    unsigned r = v.u + 0x7fffu + ((v.u >> 16) & 1u);
    return (u16)(r >> 16);
}
__device__ __forceinline__ float f_of_bf16(u16 h){
    union { unsigned u; float f; } v; v.u = ((unsigned)h) << 16; return v.f;
}
__device__ __forceinline__ void split2(float x, u16* hi, u16* lo){
    u16 h = bf16_of(x);
    *hi = h;
    *lo = bf16_of(x - f_of_bf16(h));
}

// Fragment-packed layouts: packed(row, k):
//   addr = TILE*512 + ((k>>3)&3)*128 + (row&15)*8 + (k&7)
// wave fragment load = lane*16B fully coalesced.

// ==================== MFMA PATH ====================

// merged prep: regions by blockIdx.x
//  [0,4096)      DfB basis      (1,048,576 elems)
//  [4096,8192)   DiB basis      (1,048,576)
//  [8192,8224)   p1 pack        (8,192)
//  [8224,16416)  hB lift        (2,097,152 threads x8)
//  [16416,17440) Hf0 closed form(262,144)
__global__ void k_prep_all(const float* __restrict__ x, const float* __restrict__ lw,
                           const float* __restrict__ lb, const float* __restrict__ p1w,
                           u16* __restrict__ dfh, u16* __restrict__ dfl,
                           u16* __restrict__ dih, u16* __restrict__ dil,
                           u16* __restrict__ p1h, u16* __restrict__ p1l,
                           u16* __restrict__ hBh, u16* __restrict__ hBl,
                           float* __restrict__ Hf){
    const int bid = blockIdx.x;
    if(bid < 4096){
        int t = bid * 256 + threadIdx.x;
        int s = t & 7, r = (t >> 3) & 15, g = (t >> 7) & 3;
        int nc = (t >> 9) & 255, jt = t >> 17;
        int j = jt * 16 + r, n = nc * 32 + g * 8 + s, k = j & 63;
        int rr = (k * n) & (NGRID - 1);
        float sn, cs;
        sincosf((float)rr * 7.6699039394282061e-4f, &sn, &cs);
        float val = (j < 64) ? cs : sn;
        u16 h, l; split2(val, &h, &l);
        dfh[t] = h; dfl[t] = l;
    } else if(bid < 8192){
        int t = (bid - 4096) * 256 + threadIdx.x;
        int s = t & 7, r = (t >> 3) & 15, g = (t >> 7) & 3;
        int kt = (t >> 9) & 3, nt = t >> 11;
        int n = nt * 16 + r, k = kt * 32 + g * 8 + s, kk = k & 63;
        int rr = (kk * n) & (NGRID - 1);
        float sn, cs;
        sincosf((float)rr * 7.6699039394282061e-4f, &sn, &cs);
        float val = (k < 64) ? cs : sn;
        u16 h, l; split2(val, &h, &l);
        dih[t] = h; dil[t] = l;
    } else if(bid < 8224){
        int t = (bid - 8192) * 256 + threadIdx.x;
        int s = t & 7, r = (t >> 3) & 15, g = (t >> 7) & 3;
        int kt = (t >> 9) & 1, jt = t >> 10;
        int j = jt * 16 + r, c = kt * 32 + g * 8 + s;
        u16 h, l; split2(p1w[j * 64 + c], &h, &l);
        p1h[t] = h; p1l[t] = l;
    } else if(bid < 16416){
        int T = (bid - 8224) * 256 + threadIdx.x;
        int r = T & 15, g = (T >> 4) & 3;
        int kt = (T >> 6) & 1, nt = (T >> 7) & 511, b = T >> 16;
        int n = nt * 16 + r;
        int cbase = kt * 32 + g * 8;
        const float gr = (float)n * (1.0f/8191.0f);
        bf16x8 vh, vl;
        #pragma unroll
        for(int s = 0; s < 8; s++){
            const int c = cbase + s;
            float A = lb[c];
            #pragma unroll
            for(int d = 0; d < 5; d++) A = fmaf(x[b*5 + d], lw[c*6 + d], A);
            float val = fmaf(gr, lw[c*6 + 5], A);
            u16 h, l; split2(val, &h, &l);
            vh[s] = (short)h; vl[s] = (short)l;
        }
        *(bf16x8*)(hBh + (size_t)T*8) = vh;
        *(bf16x8*)(hBl + (size_t)T*8) = vl;
    } else {
        int t = (bid - 16416) * 256 + threadIdx.x;
        int j = t & 127, c = (t >> 7) & 63, b = t >> 13;
        float A = lb[c];
        #pragma unroll
        for(int d = 0; d < 5; d++) A = fmaf(x[b*5 + d], lw[c*6 + d], A);
        const float v = lw[c*6 + 5];
        float val;
        if(j < 64){
            val = (j == 0) ? fmaf(8192.f, A, 4096.f * v)
                           : (-4096.f/8191.f) * v;
        } else {
            int jj = j - 64;
            if(jj == 0) val = 0.f;
            else {
                float sn, cs;
                sincosf((float)jj * 3.8349519697141029e-4f, &sn, &cs);  // pi/8192
                val = (-4096.f/8191.f) * v * (cs / sn);
            }
        }
        Hf[t] = val;
    }
}

// f16 reduce: 65536 threads x f16x4 -> f32x4
__global__ void k_reduce_h(const f16* __restrict__ part, float* __restrict__ Hf, int splits){
    const int t = blockIdx.x*256 + threadIdx.x;   // 65536
    f32x4 s = (f32x4){0.f,0.f,0.f,0.f};
    for(int i=0;i<splits;i++){
        f16x4 v = *(const f16x4*)(part + (size_t)i*(2048*128) + (size_t)t*4);
        s[0] += (float)v[0];
        s[1] += (float)v[1];
        s[2] += (float)v[2];
        s[3] += (float)v[3];
    }
    *(f32x4*)(Hf + (size_t)t*4) = s;
}

// f32 reduce (fallback path)
__global__ void k_reduce(const float* __restrict__ part, float* __restrict__ Hf, int splits){
    const int t = blockIdx.x*256 + threadIdx.x;   // 65536
    f32x4 s = (f32x4){0.f,0.f,0.f,0.f};
    for(int i=0;i<splits;i++){
        f32x4 v = *(const f32x4*)(part + (size_t)i*(2048*128) + (size_t)t*4);
        s += v;
    }
    *(f32x4*)(Hf + (size_t)t*4) = s;
}

// mode mix: Hf[b] staged in LDS, TLP-preserving grid.
// grid (32 b x 16 o-groups) = 512 blocks, block 256 = 4 waves;
// wave = one o (o = og*4 + w), lane = k. 2048 waves total.
__global__ __launch_bounds__(256) void k_mix_m(const float* __restrict__ Hf,
        const float* __restrict__ spW, const float* __restrict__ wcw,
        u16* __restrict__ Uhi, u16* __restrict__ Ulo, int l){
    const int b  = blockIdx.x >> 4;
    const int og = blockIdx.x & 15;
    const int tid = threadIdx.x;
    const int w = tid >> 6, k = tid & 63;
    const int o = og*4 + w;
    __shared__ float hf[8192];               // 32 KB: Hf[b][i][128]
    {
        const f32x4* src = (const f32x4*)(Hf + (size_t)b*8192);
        f32x4* dst = (f32x4*)hf;
        #pragma unroll
        for(int q=0;q<8;q++) dst[q*256 + tid] = src[q*256 + tid];
    }
    __syncthreads();

    const float* W = spW + (size_t)l*524288;
    float ar = 0.f, ai = 0.f;
    for(int i=0;i<64;i++){
        const float hr = hf[i*128 + k];
        const float hs = hf[i*128 + 64 + k];
        const float* wp = W + (((size_t)i*64 + o)*64 + k)*2;
        const float wr = wp[0], wi = wp[1];
        ar = fmaf(hr, wr, fmaf(hs, wi, ar));
        ai = fmaf(hr, wi, fmaf(-hs, wr, ai));
    }
    const float ck = (k==0) ? (1.0f/8192.0f) : (2.0f/8192.0f);
    const size_t tbase = (size_t)(b*4 + (o>>4))*6;
    const size_t sub = (size_t)((k>>3)&3)*128 + (size_t)(o&15)*8 + (size_t)(k&7);
    u16 h, lo;
    split2(ck * ar, &h, &lo);
    Uhi[(tbase + (k>>5))*512 + sub] = h;      Ulo[(tbase + (k>>5))*512 + sub] = lo;
    split2(-ck * ai, &h, &lo);
    Uhi[(tbase + 2 + (k>>5))*512 + sub] = h;  Ulo[(tbase + 2 + (k>>5))*512 + sub] = lo;
    split2(wcw[(size_t)l*4096 + o*64 + k], &h, &lo);
    Uhi[(tbase + 4 + (k>>5))*512 + sub] = h;  Ulo[(tbase + 4 + (k>>5))*512 + sub] = lo;
}

// fused inv-DFT + 1x1 conv + gelu + forward-DFT partials (l<3) or proj (l==3)
// grid (64 n-tiles of 128, 32 b), block 256 = 4 waves; wave tile 64(o) x 32(n)
// 38.9KB LDS, conflict-friendly pitches (row stride = 12 mod 32 dwords)
__global__ __launch_bounds__(256) void k_apply_m(const u16* __restrict__ Uhi,
        const u16* __restrict__ Ulo, const u16* __restrict__ Dihi,
        const u16* __restrict__ Dilo, const float* __restrict__ wcb,
        const u16* __restrict__ DfBh, const u16* __restrict__ DfBl,
        u16* __restrict__ hB_hi, u16* __restrict__ hB_lo,
        f16* __restrict__ part,
        const u16* __restrict__ p1h, const u16* __restrict__ p1l,
        const float* __restrict__ p1b, const float* __restrict__ p2w,
        const float* __restrict__ p2b, float* __restrict__ out,
        int l, int do_dft){
    const int n0 = blockIdx.x * 128;
    const int b  = blockIdx.y;
    const int tid = threadIdx.x, w = tid >> 6, lane = tid & 63;
    const int r = lane & 15, g = lane >> 4;
    const int lofs = g * 128 + r * 8;
    const int nw = n0 + w*32;
    __shared__ __align__(16) u16 tl[19456];   // 38,912 B
    // view 1 (transpose): [4][32][152]  hi at col c, lo at col 72+c   (76 dw stride)
    // view 2 (DFT stage): [64][280]     hi at col nl, lo at col 136+nl (140 dw stride)
    f32x4 acc[4][2];
    #pragma unroll
    for(int i=0;i<4;i++)
        #pragma unroll
        for(int j=0;j<2;j++) acc[i][j] = (f32x4){0.f,0.f,0.f,0.f};

    // kt 0..3: B = Dinv; kt 4..5: B = hB. B outer, A (L1-resident U) inner.
    #pragma unroll
    for(int kt=0;kt<6;kt++){
        #pragma unroll
        for(int ct=0;ct<2;ct++){
            const int nt = (nw >> 4) + ct;
            bf16x8 bh, bl;
            if(kt < 4){
                const size_t o = ((size_t)(nt*4 + kt))*512 + lofs;
                bh = *(const bf16x8*)(Dihi + o);
                bl = *(const bf16x8*)(Dilo + o);
            } else {
                const size_t o = ((size_t)((b*512 + nt)*2 + (kt-4)))*512 + lofs;
                bh = *(const bf16x8*)(hB_hi + o);
                bl = *(const bf16x8*)(hB_lo + o);
            }
            #pragma unroll
            for(int rt=0;rt<4;rt++){
                const size_t o = ((size_t)((b*4 + rt)*6 + kt))*512 + lofs;
                bf16x8 ah = *(const bf16x8*)(Uhi + o);
                bf16x8 al = *(const bf16x8*)(Ulo + o);
                acc[rt][ct] = __builtin_amdgcn_mfma_f32_16x16x32_bf16(
                    ah, bh, acc[rt][ct], 0, 0, 0);
                acc[rt][ct] = __builtin_amdgcn_mfma_f32_16x16x32_bf16(
                    ah, bl, acc[rt][ct], 0, 0, 0);
                acc[rt][ct] = __builtin_amdgcn_mfma_f32_16x16x32_bf16(
                    al, bh, acc[rt][ct], 0, 0, 0);
            }
        }
    }
    // epilogue: bias + gelu
    #pragma unroll
    for(int rt=0;rt<4;rt++)
        #pragma unroll
        for(int q=0;q<4;q++){
            const int o = rt*16 + g*4 + q;
            const float bias = wcb[l*64 + o];
            #pragma unroll
            for(int ct=0;ct<2;ct++)
                acc[rt][ct][q] = gelu_f(acc[rt][ct][q] + bias);
        }

    // ---- hB single-pass: LDS [wave][n-sub 32][152] (hi cols 0..63, lo cols 72..135) ----
    // split results carried in registers (svh/svl) for reuse by the DFT restage.
    sh4 svh[4][2], svl[4][2];
    #pragma unroll
    for(int rt=0;rt<4;rt++)
        #pragma unroll
        for(int ct=0;ct<2;ct++){
            sh4 vh_, vl_;
            #pragma unroll
            for(int q=0;q<4;q++){
                float val = acc[rt][ct][q];
                u16 hh = bf16_of(val);
                vh_[q] = (short)hh;
                vl_[q] = (short)bf16_of(val - f_of_bf16(hh));
            }
            svh[rt][ct] = vh_;
            svl[rt][ct] = vl_;
            const int base = w*(32*152) + (ct*16 + r)*152 + rt*16 + g*4;
            *(sh4*)&tl[base]      = vh_;
            *(sh4*)&tl[base + 72] = vl_;
        }
    __syncthreads();
    if(do_dft){
        // global hB store (only needed when a later layer reads it)
        const int row_local = tid >> 1, half = tid & 1;
        const int ww = row_local >> 5, nn = row_local & 31;
        const int n = n0 + row_local;
        const int nt = n >> 4, rr = n & 15;
        const int base = ww*(32*152) + nn*152 + half*32;
        const size_t dof = ((size_t)((b*512 + nt)*2 + half))*512 + rr*8;
        #pragma unroll
        for(int s=0;s<4;s++){
            bf16x8 v = *(const bf16x8*)&tl[base + s*8];
            *(bf16x8*)(hB_hi + dof + s*128) = v;
        }
        #pragma unroll
        for(int s=0;s<4;s++){
            bf16x8 v = *(const bf16x8*)&tl[base + 72 + s*8];
            *(bf16x8*)(hB_lo + dof + s*128) = v;
        }
    }
    __syncthreads();

    if(do_dft){
        // ---- fused forward DFT: restage hi+lo in LDS [64c][280] from registers ----
        #pragma unroll
        for(int rt=0;rt<4;rt++)
            #pragma unroll
            for(int ct=0;ct<2;ct++)
                #pragma unroll
                for(int q=0;q<4;q++){
                    const int o0 = rt*16 + g*4 + q;
                    const int nl = w*32 + ct*16 + r;
                    tl[o0*280 + nl]       = (u16)svh[rt][ct][q];
                    tl[o0*280 + 136 + nl] = (u16)svl[rt][ct][q];
                }
        __syncthreads();

        f32x4 acc2[4][2];
        #pragma unroll
        for(int cc=0;cc<4;cc++)
            #pragma unroll
            for(int jj=0;jj<2;jj++) acc2[cc][jj] = (f32x4){0.f,0.f,0.f,0.f};
        const int jt0 = w*2;
        const int ncb = n0 >> 5;

        #pragma unroll
        for(int nc4=0;nc4<4;nc4++){
            #pragma unroll
            for(int jj=0;jj<2;jj++){
                const size_t o = ((size_t)((jt0+jj)*256 + ncb + nc4))*512 + lofs;
                bf16x8 bh2 = *(const bf16x8*)(DfBh + o);
                bf16x8 bl2 = *(const bf16x8*)(DfBl + o);
                #pragma unroll
                for(int cc=0;cc<4;cc++){
                    const int abase = (cc*16 + r)*280 + nc4*32 + g*8;
                    bf16x8 ah = *(const bf16x8*)&tl[abase];
                    bf16x8 al = *(const bf16x8*)&tl[abase + 136];
                    acc2[cc][jj] = __builtin_amdgcn_mfma_f32_16x16x32_bf16(
                        ah, bh2, acc2[cc][jj], 0, 0, 0);
                    acc2[cc][jj] = __builtin_amdgcn_mfma_f32_16x16x32_bf16(
                        ah, bl2, acc2[cc][jj], 0, 0, 0);
                    acc2[cc][jj] = __builtin_amdgcn_mfma_f32_16x16x32_bf16(
                        al, bh2, acc2[cc][jj], 0, 0, 0);
                }
            }
        }
        // write part[ntile][b][c][j] as f16
        f16* P = part + ((size_t)blockIdx.x*32 + b)*8192;
        #pragma unroll
        for(int cc=0;cc<4;cc++)
            #pragma unroll
            for(int jj=0;jj<2;jj++)
                #pragma unroll
                for(int q=0;q<4;q++)
                    P[(size_t)(cc*16 + g*4 + q)*128 + (jt0+jj)*16 + r] =
                        (f16)acc2[cc][jj][q];
    } else {
        // ---- fused projection (l==3): out = p2 . gelu(p1 @ h + p1b) + p2b ----
        f32x4 acc3[8][2];
        #pragma unroll
        for(int jt=0;jt<8;jt++)
            #pragma unroll
            for(int ctn=0;ctn<2;ctn++) acc3[jt][ctn] = (f32x4){0.f,0.f,0.f,0.f};

        #pragma unroll
        for(int kc=0;kc<2;kc++){
            bf16x8 bh3[2], bl3[2];
            #pragma unroll
            for(int ctn=0;ctn<2;ctn++){
                const int base = w*(32*152) + (ctn*16 + r)*152 + kc*32 + g*8;
                bh3[ctn] = *(const bf16x8*)&tl[base];
                bl3[ctn] = *(const bf16x8*)&tl[base + 72];
            }
            #pragma unroll
            for(int jt=0;jt<8;jt++){
                const size_t oa = ((size_t)(jt*2 + kc))*512 + lofs;
                bf16x8 ah = *(const bf16x8*)(p1h + oa);
                bf16x8 al = *(const bf16x8*)(p1l + oa);
                #pragma unroll
                for(int ctn=0;ctn<2;ctn++){
                    acc3[jt][ctn] = __builtin_amdgcn_mfma_f32_16x16x32_bf16(
                        ah, bh3[ctn], acc3[jt][ctn], 0, 0, 0);
                    acc3[jt][ctn] = __builtin_amdgcn_mfma_f32_16x16x32_bf16(
                        ah, bl3[ctn], acc3[jt][ctn], 0, 0, 0);
                    acc3[jt][ctn] = __builtin_amdgcn_mfma_f32_16x16x32_bf16(
                        al, bh3[ctn], acc3[jt][ctn], 0, 0, 0);
                }
            }
        }
        #pragma unroll
        for(int ctn=0;ctn<2;ctn++){
            float pd = 0.f;
            #pragma unroll
            for(int jt=0;jt<8;jt++)
                #pragma unroll
                for(int q=0;q<4;q++){
                    const int j = jt*16 + g*4 + q;
                    pd = fmaf(p2w[j], gelu_f(acc3[jt][ctn][q] + p1b[j]), pd);
                }
            pd += __shfl_xor(pd, 16, 64);
            pd += __shfl_xor(pd, 32, 64);
            if(g == 0)
                out[(size_t)b*NGRID + n0 + w*32 + ctn*16 + r] = pd + p2b[0];
        }
    }
}

// ==================== FP32 FALLBACK PATH ====================

__global__ void k_basis_fwd(float* __restrict__ D){
    int t = blockIdx.x * 256 + threadIdx.x;
    int n = t >> 7, j = t & 127, k = j & 63;
    int r = (k * n) & (NGRID - 1);
    float s, c;
    sincosf((float)r * 7.6699039394282061e-4f, &s, &c);
    D[t] = (j < 64) ? c : s;
}

__global__ void k_basis_inv(float* __restrict__ D){
    int t = blockIdx.x * 256 + threadIdx.x;
    int j = t >> 13, n = t & (NGRID - 1), k = j & 63;
    int r = (k * n) & (NGRID - 1);
    float s, c;
    sincosf((float)r * 7.6699039394282061e-4f, &s, &c);
    D[t] = (j < 64) ? c : s;
}

__global__ void k_lift(const float* __restrict__ x, const float* __restrict__ lw,
                       const float* __restrict__ lb, float* __restrict__ h){
    const int bc = blockIdx.x;
    const int b = bc >> 6, c = bc & 63;
    float A = lb[c];
    #pragma unroll
    for(int d = 0; d < 5; d++) A = fmaf(x[b*5 + d], lw[c*6 + d], A);
    const float v = lw[c*6 + 5];
    float* hp = h + (size_t)bc * NGRID;
    for(int n = threadIdx.x; n < NGRID; n += 256)
        hp[n] = fmaf((float)n * (1.0f/8191.0f), v, A);
}

__global__ __launch_bounds__(256) void k_dft(const float* __restrict__ h,
                                             const float* __restrict__ Dfwd,
                                             float* __restrict__ part,
                                             int chunk){
    const int m0 = blockIdx.x * 64;
    const int sp = blockIdx.y;
    const int kbase = sp * chunk;
    __shared__ float AsT[32][68];
    __shared__ float Bs[32][128];
    const int tid = threadIdx.x;
    const int tr = tid >> 4;
    const int tc = tid & 15;
    float acc[4][8];
    #pragma unroll
    for(int u=0;u<4;u++)
        #pragma unroll
        for(int v=0;v<8;v++) acc[u][v] = 0.f;

    for(int k0 = kbase; k0 < kbase + chunk; k0 += 32){
        {
            const int kk = tid & 31, r0 = tid >> 5;
            #pragma unroll
            for(int p=0;p<8;p++){
                const int row = r0 + p*8;
                AsT[kk][row] = h[(size_t)(m0+row)*NGRID + k0 + kk];
            }
        }
        {
            const int j = tid & 127, kb = tid >> 7;
            #pragma unroll
            for(int q=0;q<16;q++){
                const int kk = kb + q*2;
                Bs[kk][j] = Dfwd[(size_t)(k0+kk)*128 + j];
            }
        }
        __syncthreads();
        #pragma unroll
        for(int kk=0;kk<32;kk++){
            float a[4], bv[8];
            #pragma unroll
            for(int u=0;u<4;u++) a[u] = AsT[kk][tr*4+u];
            #pragma unroll
            for(int v=0;v<8;v++) bv[v] = Bs[kk][tc*8+v];
            #pragma unroll
            for(int u=0;u<4;u++)
                #pragma unroll
                for(int v=0;v<8;v++)
                    acc[u][v] = fmaf(a[u], bv[v], acc[u][v]);
        }
        __syncthreads();
    }
    float* P = part + (size_t)sp * (2048*128);
    #pragma unroll
    for(int u=0;u<4;u++){
        const int row = m0 + tr*4 + u;
        #pragma unroll
        for(int v=0;v<8;v++)
            P[(size_t)row*128 + tc*8 + v] = acc[u][v];
    }
}

__global__ __launch_bounds__(64) void k_mix(const float* __restrict__ Hf,
        const float* __restrict__ spW, const float* __restrict__ wcw,
        float* __restrict__ U, int l){
    const int bo = blockIdx.x;
    const int b = bo >> 6, o = bo & 63;
    const int k = threadIdx.x;
    const float* Hb = Hf + (size_t)b*64*128;
    const float* W = spW + (size_t)l*64*64*64*2;
    float ar = 0.f, ai = 0.f;
    for(int i=0;i<64;i++){
        const float hr = Hb[i*128 + k];
        const float hs = Hb[i*128 + 64 + k];
        const float* wp = W + (((size_t)i*64 + o)*64 + k)*2;
        const float wr = wp[0], wi = wp[1];
        ar = fmaf(hr, wr, fmaf(hs, wi, ar));
        ai = fmaf(hr, wi, fmaf(-hs, wr, ai));
    }
    const float ck = (k==0) ? (1.0f/8192.0f) : (2.0f/8192.0f);
    float* Ub = U + (size_t)bo * 192;
    Ub[k]       = ck * ar;
    Ub[64 + k]  = -ck * ai;
    Ub[128 + k] = wcw[(size_t)l*4096 + o*64 + k];
}

__global__ __launch_bounds__(256) void k_apply(const float* __restrict__ U,
                                               const float* __restrict__ Dinv,
                                               const float* __restrict__ wcb,
                                               float* __restrict__ h,
                                               int l){
    const int n0 = blockIdx.x * 128;
    const int b  = blockIdx.y;
    __shared__ float UsT[32][68];
    __shared__ float Vs[32][128];
    const int tid = threadIdx.x, tr = tid >> 4, tc = tid & 15;
    float acc[4][8];
    #pragma unroll
    for(int u=0;u<4;u++)
        #pragma unroll
        for(int v=0;v<8;v++) acc[u][v] = 0.f;
    const float* Ub = U + (size_t)b * (64*192);

    for(int k0=0;k0<192;k0+=32){
        {
            const int kk = tid & 31, r0 = tid >> 5;
            #pragma unroll
            for(int p=0;p<8;p++){
                const int o = r0 + p*8;
                UsT[kk][o] = Ub[o*192 + k0 + kk];
            }
        }
        {
            const int j = tid & 127, kb = tid >> 7;
            #pragma unroll
            for(int q=0;q<16;q++){
                const int kk = kb + q*2;
                const int kg = k0 + kk;
                const float* rp = (kg < 128) ? (Dinv + (size_t)kg*NGRID)
                                             : (h + ((size_t)b*64 + (kg-128))*NGRID);
                Vs[kk][j] = rp[n0 + j];
            }
        }
        __syncthreads();
        #pragma unroll
        for(int kk=0;kk<32;kk++){
            float a[4], bv[8];
            #pragma unroll
            for(int u=0;u<4;u++) a[u] = UsT[kk][tr*4+u];
            #pragma unroll
            for(int v=0;v<8;v++) bv[v] = Vs[kk][tc*8+v];
            #pragma unroll
            for(int u=0;u<4;u++)
                #pragma unroll
                for(int v=0;v<8;v++)
                    acc[u][v] = fmaf(a[u], bv[v], acc[u][v]);
        }
        __syncthreads();
    }
    #pragma unroll
    for(int u=0;u<4;u++){
        const int o = tr*4 + u;
        const float bias = wcb[l*64 + o];
        float* hp = h + ((size_t)b*64 + o)*NGRID + n0 + tc*8;
        #pragma unroll
        for(int v=0;v<8;v++)
            hp[v] = gelu_f(acc[u][v] + bias);
    }
}

__global__ __launch_bounds__(256) void k_proj(const float* __restrict__ h,
        const float* __restrict__ p1w, const float* __restrict__ p1b,
        const float* __restrict__ p2w, const float* __restrict__ p2b,
        float* __restrict__ out){
    const int n0 = blockIdx.x * 128;
    const int b  = blockIdx.y;
    __shared__ float Hs[64][128];
    __shared__ float P1T[64][128];
    const int tid = threadIdx.x, tr = tid >> 4, tc = tid & 15;
    {
        const int j = tid & 127, cb = tid >> 7;
        #pragma unroll
        for(int q=0;q<32;q++){
            const int c = cb + q*2;
            Hs[c][j] = h[((size_t)b*64 + c)*NGRID + n0 + j];
        }
    }
    {
        #pragma unroll
        for(int q=0;q<32;q++){
            const int e = q*256 + tid;
            const int j = e & 127, c = e >> 7;
            P1T[c][j] = p1w[j*64 + c];
        }
    }
    __syncthreads();
    float acc[8][8];
    #pragma unroll
    for(int u=0;u<8;u++)
        #pragma unroll
        for(int v=0;v<8;v++) acc[u][v] = 0.f;
    for(int c=0;c<64;c++){
        float pv[8], hv[8];
        #pragma unroll
        for(int u=0;u<8;u++) pv[u] = P1T[c][tr*8+u];
        #pragma unroll
        for(int v=0;v<8;v++) hv[v] = Hs[c][tc*8+v];
        #pragma unroll
        for(int u=0;u<8;u++)
            #pragma unroll
            for(int v=0;v<8;v++)
                acc[u][v] = fmaf(pv[u], hv[v], acc[u][v]);
    }
    float pd[8];
    #pragma unroll
    for(int v=0;v<8;v++) pd[v] = 0.f;
    #pragma unroll
    for(int u=0;u<8;u++){
        const int j = tr*8 + u;
        const float bj = p1b[j], wj = p2w[j];
        #pragma unroll
        for(int v=0;v<8;v++)
            pd[v] = fmaf(wj, gelu_f(acc[u][v] + bj), pd[v]);
    }
    __syncthreads();
    float* red = &P1T[0][0];
    #pragma unroll
    for(int v=0;v<8;v++) red[tr*128 + tc*8 + v] = pd[v];
    __syncthreads();
    if(tid < 128){
        float sY = p2b[0];
        #pragma unroll
        for(int r=0;r<16;r++) sY += red[r*128 + tid];
        out[(size_t)b*NGRID + n0 + tid] = sY;
    }
}

// ==================== LAUNCH ====================

extern "C" void kernel_launch(void* const* d_in, const int* in_sizes, int n_in,
                              void* d_out, int out_size, void* d_ws, size_t ws_size,
                              hipStream_t stream){
    const float* x   = (const float*)d_in[0];
    const float* lw  = (const float*)d_in[1];
    const float* lb  = (const float*)d_in[2];
    const float* spW = (const float*)d_in[3];
    const float* wcw = (const float*)d_in[4];
    const float* wcb = (const float*)d_in[5];
    const float* p1w = (const float*)d_in[6];
    const float* p1b = (const float*)d_in[7];
    const float* p2w = (const float*)d_in[8];
    const float* p2b = (const float*)d_in[9];
    float* out = (float*)d_out;

    const size_t N_H   = (size_t)32*64*NGRID;   // 16,777,216
    const size_t N_D   = (size_t)128*NGRID;     // 1,048,576
    const size_t N_U   = (size_t)32*64*192;     // 393,216
    const size_t N_P1  = 8192;
    // u16 arrays: hB(2) + Df(2) + Di(2) + U(2) + p1(2)
    const size_t ush_total = 2*N_H + 4*N_D + 2*N_U + 2*N_P1;
    // f32 Hf + 64-way f16 part
    const size_t need_new = ush_total*2 + (size_t)262144*4 + (size_t)64*262144*2;

    if(ws_size >= need_new){
        u16* W = (u16*)d_ws;
        u16* hBh = W; W += N_H;
        u16* hBl = W; W += N_H;
        u16* dfh = W; W += N_D;
        u16* dfl = W; W += N_D;
        u16* dih = W; W += N_D;
        u16* dil = W; W += N_D;
        u16* uh  = W; W += N_U;
        u16* ul  = W; W += N_U;
        u16* p1h = W; W += N_P1;
        u16* p1l = W; W += N_P1;
        float* Hf   = (float*)W;
        f16*  part  = (f16*)(Hf + 262144);

        k_prep_all<<<dim3(17440), dim3(256), 0, stream>>>(x, lw, lb, p1w,
                                                          dfh, dfl, dih, dil,
                                                          p1h, p1l, hBh, hBl, Hf);
        for(int l=0;l<4;l++){
            k_mix_m<<<dim3(512), dim3(256), 0, stream>>>(Hf, spW, wcw, uh, ul, l);
            k_apply_m<<<dim3(64, 32), dim3(256), 0, stream>>>(uh, ul, dih, dil, wcb,
                                                             dfh, dfl, hBh, hBl,
                                                             part, p1h, p1l,
                                                             p1b, p2w, p2b, out,
                                                             l, (l<3) ? 1 : 0);
            if(l < 3)
                k_reduce_h<<<dim3(256), dim3(256), 0, stream>>>(part, Hf, 64);
        }
        return;
    }

    // ---- fallback fp32 path ----
    float* ws  = (float*)d_ws;
    float* Dfwd = ws;
    float* Dinv = Dfwd + (size_t)NGRID*128;
    float* h    = Dinv + (size_t)128*NGRID;
    float* Hf   = h    + (size_t)32*64*NGRID;
    float* U    = Hf   + (size_t)2048*128;
    float* part = U    + (size_t)32*64*192;

    const size_t fixedf = (size_t)NGRID*128*2 + (size_t)32*64*NGRID
                        + (size_t)2048*128 + (size_t)32*64*192;
    int splits = 32;
    while(splits > 1 && (fixedf + (size_t)splits*2048*128)*sizeof(float) > ws_size)
        splits >>= 1;
    const int chunk = NGRID / splits;

    k_basis_fwd<<<dim3(4096), dim3(256), 0, stream>>>(Dfwd);
    k_basis_inv<<<dim3(4096), dim3(256), 0, stream>>>(Dinv);
    k_lift<<<dim3(2048), dim3(256), 0, stream>>>(x, lw, lb, h);
    for(int l=0;l<4;l++){
        k_dft<<<dim3(32, splits), dim3(256), 0, stream>>>(h, Dfwd, part, chunk);
        k_reduce<<<dim3(256), dim3(256), 0, stream>>>(part, Hf, splits);
        k_mix<<<dim3(2048), dim3(64), 0, stream>>>(Hf, spW, wcw, U, l);
        k_apply<<<dim3(64, 32), dim3(256), 0, stream>>>(U, Dinv, wcb, h, l);
    }
    k_proj<<<dim3(64, 32), dim3(256), 0, stream>>>(h, p1w, p1b, p2w, p2b, out);
}

// Round 29
// 322.768 us; speedup vs baseline: 1.0038x; 1.0038x over previous
//
#include <hip/hip_runtime.h>
#include <math.h>

#define NGRID 8192

typedef unsigned short u16;
typedef _Float16 f16;
typedef __attribute__((ext_vector_type(4))) float f32x4;
typedef __attribute__((ext_vector_type(4))) _Float16 f16x4;
typedef __attribute__((ext_vector_type(8))) short bf16x8;
typedef __attribute__((ext_vector_type(4))) short sh4;

// fast gelu: Abramowitz-Stegun 7.1.26 erf, |abs err| <= 1.5e-7
__device__ __forceinline__ float gelu_f(float x){
    float z = fabsf(x) * 0.70710678118654752f;
    float t = __builtin_amdgcn_rcpf(fmaf(0.3275911f, z, 1.0f));
    float p = fmaf(fmaf(fmaf(fmaf(1.061405429f, t, -1.453152027f), t,
                1.421413741f), t, -0.284496736f), t, 0.254829592f) * t;
    float er = 1.0f - p * __expf(-z*z);
    float s = (x >= 0.0f) ? er : -er;
    return 0.5f * x * (1.0f + s);
}

__device__ __forceinline__ u16 bf16_of(float x){
    union { float f; unsigned u; } v; v.f = x;
    unsigned r = v.u + 0x7fffu + ((v.u >> 16) & 1u);
    return (u16)(r >> 16);
}
__device__ __forceinline__ float f_of_bf16(u16 h){
    union { unsigned u; float f; } v; v.u = ((unsigned)h) << 16; return v.f;
}
__device__ __forceinline__ void split2(float x, u16* hi, u16* lo){
    u16 h = bf16_of(x);
    *hi = h;
    *lo = bf16_of(x - f_of_bf16(h));
}

// LDS swizzles (32KB views, XOR spreads banks; preserves 8B/16B alignment)
__device__ __forceinline__ int sw1(int row, int col){  // view1 [32][128] u16 per wave
    return row*128 + (col ^ ((row & 7) << 3));
}
__device__ __forceinline__ int sw2(int c, int col){    // view2 [64][256] u16
    return c*256 + (col ^ ((c & 7) << 3));
}

// Fragment-packed layouts: packed(row, k):
//   addr = TILE*512 + ((k>>3)&3)*128 + (row&15)*8 + (k&7)
// wave fragment load = lane*16B fully coalesced.

// ==================== MFMA PATH ====================

// merged prep: regions by blockIdx.x
//  [0,4096)      DfB basis      (1,048,576 elems)
//  [4096,8192)   DiB basis      (1,048,576)
//  [8192,8224)   p1 pack        (8,192)
//  [8224,16416)  hB lift        (2,097,152 threads x8)
//  [16416,17440) Hf0 closed form(262,144)
__global__ void k_prep_all(const float* __restrict__ x, const float* __restrict__ lw,
                           const float* __restrict__ lb, const float* __restrict__ p1w,
                           u16* __restrict__ dfh, u16* __restrict__ dfl,
                           u16* __restrict__ dih, u16* __restrict__ dil,
                           u16* __restrict__ p1h, u16* __restrict__ p1l,
                           u16* __restrict__ hBh, u16* __restrict__ hBl,
                           float* __restrict__ Hf){
    const int bid = blockIdx.x;
    if(bid < 4096){
        int t = bid * 256 + threadIdx.x;
        int s = t & 7, r = (t >> 3) & 15, g = (t >> 7) & 3;
        int nc = (t >> 9) & 255, jt = t >> 17;
        int j = jt * 16 + r, n = nc * 32 + g * 8 + s, k = j & 63;
        int rr = (k * n) & (NGRID - 1);
        float sn, cs;
        sincosf((float)rr * 7.6699039394282061e-4f, &sn, &cs);
        float val = (j < 64) ? cs : sn;
        u16 h, l; split2(val, &h, &l);
        dfh[t] = h; dfl[t] = l;
    } else if(bid < 8192){
        int t = (bid - 4096) * 256 + threadIdx.x;
        int s = t & 7, r = (t >> 3) & 15, g = (t >> 7) & 3;
        int kt = (t >> 9) & 3, nt = t >> 11;
        int n = nt * 16 + r, k = kt * 32 + g * 8 + s, kk = k & 63;
        int rr = (kk * n) & (NGRID - 1);
        float sn, cs;
        sincosf((float)rr * 7.6699039394282061e-4f, &sn, &cs);
        float val = (k < 64) ? cs : sn;
        u16 h, l; split2(val, &h, &l);
        dih[t] = h; dil[t] = l;
    } else if(bid < 8224){
        int t = (bid - 8192) * 256 + threadIdx.x;
        int s = t & 7, r = (t >> 3) & 15, g = (t >> 7) & 3;
        int kt = (t >> 9) & 1, jt = t >> 10;
        int j = jt * 16 + r, c = kt * 32 + g * 8 + s;
        u16 h, l; split2(p1w[j * 64 + c], &h, &l);
        p1h[t] = h; p1l[t] = l;
    } else if(bid < 16416){
        int T = (bid - 8224) * 256 + threadIdx.x;
        int r = T & 15, g = (T >> 4) & 3;
        int kt = (T >> 6) & 1, nt = (T >> 7) & 511, b = T >> 16;
        int n = nt * 16 + r;
        int cbase = kt * 32 + g * 8;
        const float gr = (float)n * (1.0f/8191.0f);
        bf16x8 vh, vl;
        #pragma unroll
        for(int s = 0; s < 8; s++){
            const int c = cbase + s;
            float A = lb[c];
            #pragma unroll
            for(int d = 0; d < 5; d++) A = fmaf(x[b*5 + d], lw[c*6 + d], A);
            float val = fmaf(gr, lw[c*6 + 5], A);
            u16 h, l; split2(val, &h, &l);
            vh[s] = (short)h; vl[s] = (short)l;
        }
        *(bf16x8*)(hBh + (size_t)T*8) = vh;
        *(bf16x8*)(hBl + (size_t)T*8) = vl;
    } else {
        int t = (bid - 16416) * 256 + threadIdx.x;
        int j = t & 127, c = (t >> 7) & 63, b = t >> 13;
        float A = lb[c];
        #pragma unroll
        for(int d = 0; d < 5; d++) A = fmaf(x[b*5 + d], lw[c*6 + d], A);
        const float v = lw[c*6 + 5];
        float val;
        if(j < 64){
            val = (j == 0) ? fmaf(8192.f, A, 4096.f * v)
                           : (-4096.f/8191.f) * v;
        } else {
            int jj = j - 64;
            if(jj == 0) val = 0.f;
            else {
                float sn, cs;
                sincosf((float)jj * 3.8349519697141029e-4f, &sn, &cs);  // pi/8192
                val = (-4096.f/8191.f) * v * (cs / sn);
            }
        }
        Hf[t] = val;
    }
}

// f16 reduce: 65536 threads x f16x4 -> f32x4
__global__ void k_reduce_h(const f16* __restrict__ part, float* __restrict__ Hf, int splits){
    const int t = blockIdx.x*256 + threadIdx.x;   // 65536
    f32x4 s = (f32x4){0.f,0.f,0.f,0.f};
    for(int i=0;i<splits;i++){
        f16x4 v = *(const f16x4*)(part + (size_t)i*(2048*128) + (size_t)t*4);
        s[0] += (float)v[0];
        s[1] += (float)v[1];
        s[2] += (float)v[2];
        s[3] += (float)v[3];
    }
    *(f32x4*)(Hf + (size_t)t*4) = s;
}

// f32 reduce (fallback path)
__global__ void k_reduce(const float* __restrict__ part, float* __restrict__ Hf, int splits){
    const int t = blockIdx.x*256 + threadIdx.x;   // 65536
    f32x4 s = (f32x4){0.f,0.f,0.f,0.f};
    for(int i=0;i<splits;i++){
        f32x4 v = *(const f32x4*)(part + (size_t)i*(2048*128) + (size_t)t*4);
        s += v;
    }
    *(f32x4*)(Hf + (size_t)t*4) = s;
}

// mode mix: Hf[b] staged in LDS, TLP-preserving grid.
// grid (32 b x 16 o-groups) = 512 blocks, block 256 = 4 waves;
// wave = one o (o = og*4 + w), lane = k. 2048 waves total.
__global__ __launch_bounds__(256) void k_mix_m(const float* __restrict__ Hf,
        const float* __restrict__ spW, const float* __restrict__ wcw,
        u16* __restrict__ Uhi, u16* __restrict__ Ulo, int l){
    const int b  = blockIdx.x >> 4;
    const int og = blockIdx.x & 15;
    const int tid = threadIdx.x;
    const int w = tid >> 6, k = tid & 63;
    const int o = og*4 + w;
    __shared__ float hf[8192];               // 32 KB: Hf[b][i][128]
    {
        const f32x4* src = (const f32x4*)(Hf + (size_t)b*8192);
        f32x4* dst = (f32x4*)hf;
        #pragma unroll
        for(int q=0;q<8;q++) dst[q*256 + tid] = src[q*256 + tid];
    }
    __syncthreads();

    const float* W = spW + (size_t)l*524288;
    float ar = 0.f, ai = 0.f;
    for(int i=0;i<64;i++){
        const float hr = hf[i*128 + k];
        const float hs = hf[i*128 + 64 + k];
        const float* wp = W + (((size_t)i*64 + o)*64 + k)*2;
        const float wr = wp[0], wi = wp[1];
        ar = fmaf(hr, wr, fmaf(hs, wi, ar));
        ai = fmaf(hr, wi, fmaf(-hs, wr, ai));
    }
    const float ck = (k==0) ? (1.0f/8192.0f) : (2.0f/8192.0f);
    const size_t tbase = (size_t)(b*4 + (o>>4))*6;
    const size_t sub = (size_t)((k>>3)&3)*128 + (size_t)(o&15)*8 + (size_t)(k&7);
    u16 h, lo;
    split2(ck * ar, &h, &lo);
    Uhi[(tbase + (k>>5))*512 + sub] = h;      Ulo[(tbase + (k>>5))*512 + sub] = lo;
    split2(-ck * ai, &h, &lo);
    Uhi[(tbase + 2 + (k>>5))*512 + sub] = h;  Ulo[(tbase + 2 + (k>>5))*512 + sub] = lo;
    split2(wcw[(size_t)l*4096 + o*64 + k], &h, &lo);
    Uhi[(tbase + 4 + (k>>5))*512 + sub] = h;  Ulo[(tbase + 4 + (k>>5))*512 + sub] = lo;
}

// fused inv-DFT + 1x1 conv + gelu + forward-DFT partials (l<3) or proj (l==3)
// grid (64 n-tiles of 128, 32 b), block 256 = 4 waves; wave tile 64(o) x 32(n)
// 32 KB LDS (XOR-swizzled views) -> 5 blocks/CU (20 waves, was 16)
__global__ __launch_bounds__(256) void k_apply_m(const u16* __restrict__ Uhi,
        const u16* __restrict__ Ulo, const u16* __restrict__ Dihi,
        const u16* __restrict__ Dilo, const float* __restrict__ wcb,
        const u16* __restrict__ DfBh, const u16* __restrict__ DfBl,
        u16* __restrict__ hB_hi, u16* __restrict__ hB_lo,
        f16* __restrict__ part,
        const u16* __restrict__ p1h, const u16* __restrict__ p1l,
        const float* __restrict__ p1b, const float* __restrict__ p2w,
        const float* __restrict__ p2b, float* __restrict__ out,
        int l, int do_dft){
    const int n0 = blockIdx.x * 128;
    const int b  = blockIdx.y;
    const int tid = threadIdx.x, w = tid >> 6, lane = tid & 63;
    const int r = lane & 15, g = lane >> 4;
    const int lofs = g * 128 + r * 8;
    const int nw = n0 + w*32;
    __shared__ __align__(16) u16 tl[16384];   // 32,768 B
    // view 1 (transpose): per wave [32][128] u16, sw1: hi cols 0..63, lo 64..127
    // view 2 (DFT stage): [64][256] u16, sw2: hi cols 0..127, lo 128..255
    f32x4 acc[4][2];
    #pragma unroll
    for(int i=0;i<4;i++)
        #pragma unroll
        for(int j=0;j<2;j++) acc[i][j] = (f32x4){0.f,0.f,0.f,0.f};

    // kt 0..3: B = Dinv; kt 4..5: B = hB. B outer, A (L1-resident U) inner.
    #pragma unroll
    for(int kt=0;kt<6;kt++){
        #pragma unroll
        for(int ct=0;ct<2;ct++){
            const int nt = (nw >> 4) + ct;
            bf16x8 bh, bl;
            if(kt < 4){
                const size_t o = ((size_t)(nt*4 + kt))*512 + lofs;
                bh = *(const bf16x8*)(Dihi + o);
                bl = *(const bf16x8*)(Dilo + o);
            } else {
                const size_t o = ((size_t)((b*512 + nt)*2 + (kt-4)))*512 + lofs;
                bh = *(const bf16x8*)(hB_hi + o);
                bl = *(const bf16x8*)(hB_lo + o);
            }
            #pragma unroll
            for(int rt=0;rt<4;rt++){
                const size_t o = ((size_t)((b*4 + rt)*6 + kt))*512 + lofs;
                bf16x8 ah = *(const bf16x8*)(Uhi + o);
                bf16x8 al = *(const bf16x8*)(Ulo + o);
                acc[rt][ct] = __builtin_amdgcn_mfma_f32_16x16x32_bf16(
                    ah, bh, acc[rt][ct], 0, 0, 0);
                acc[rt][ct] = __builtin_amdgcn_mfma_f32_16x16x32_bf16(
                    ah, bl, acc[rt][ct], 0, 0, 0);
                acc[rt][ct] = __builtin_amdgcn_mfma_f32_16x16x32_bf16(
                    al, bh, acc[rt][ct], 0, 0, 0);
            }
        }
    }
    // epilogue: bias + gelu
    #pragma unroll
    for(int rt=0;rt<4;rt++)
        #pragma unroll
        for(int q=0;q<4;q++){
            const int o = rt*16 + g*4 + q;
            const float bias = wcb[l*64 + o];
            #pragma unroll
            for(int ct=0;ct<2;ct++)
                acc[rt][ct][q] = gelu_f(acc[rt][ct][q] + bias);
        }

    // ---- hB single-pass: view1 per wave, swizzled ----
    sh4 svh[4][2], svl[4][2];
    #pragma unroll
    for(int rt=0;rt<4;rt++)
        #pragma unroll
        for(int ct=0;ct<2;ct++){
            sh4 vh_, vl_;
            #pragma unroll
            for(int q=0;q<4;q++){
                float val = acc[rt][ct][q];
                u16 hh = bf16_of(val);
                vh_[q] = (short)hh;
                vl_[q] = (short)bf16_of(val - f_of_bf16(hh));
            }
            svh[rt][ct] = vh_;
            svl[rt][ct] = vl_;
            const int row = ct*16 + r, col = rt*16 + g*4;
            *(sh4*)&tl[w*4096 + sw1(row, col)]      = vh_;
            *(sh4*)&tl[w*4096 + sw1(row, 64 + col)] = vl_;
        }
    __syncthreads();
    if(do_dft){
        // global hB store (only needed when a later layer reads it)
        const int row_local = tid >> 1, half = tid & 1;
        const int ww = row_local >> 5, nn = row_local & 31;
        const int n = n0 + row_local;
        const int nt = n >> 4, rr = n & 15;
        const size_t dof = ((size_t)((b*512 + nt)*2 + half))*512 + rr*8;
        #pragma unroll
        for(int s=0;s<4;s++){
            bf16x8 v = *(const bf16x8*)&tl[ww*4096 + sw1(nn, half*32 + s*8)];
            *(bf16x8*)(hB_hi + dof + s*128) = v;
        }
        #pragma unroll
        for(int s=0;s<4;s++){
            bf16x8 v = *(const bf16x8*)&tl[ww*4096 + sw1(nn, 64 + half*32 + s*8)];
            *(bf16x8*)(hB_lo + dof + s*128) = v;
        }
    }
    __syncthreads();

    if(do_dft){
        // ---- fused forward DFT: restage hi+lo into view2 from registers ----
        #pragma unroll
        for(int rt=0;rt<4;rt++)
            #pragma unroll
            for(int ct=0;ct<2;ct++)
                #pragma unroll
                for(int q=0;q<4;q++){
                    const int o0 = rt*16 + g*4 + q;
                    const int nl = w*32 + ct*16 + r;
                    tl[sw2(o0, nl)]       = (u16)svh[rt][ct][q];
                    tl[sw2(o0, 128 + nl)] = (u16)svl[rt][ct][q];
                }
        __syncthreads();

        f32x4 acc2[4][2];
        #pragma unroll
        for(int cc=0;cc<4;cc++)
            #pragma unroll
            for(int jj=0;jj<2;jj++) acc2[cc][jj] = (f32x4){0.f,0.f,0.f,0.f};
        const int jt0 = w*2;
        const int ncb = n0 >> 5;

        #pragma unroll
        for(int nc4=0;nc4<4;nc4++){
            #pragma unroll
            for(int jj=0;jj<2;jj++){
                const size_t o = ((size_t)((jt0+jj)*256 + ncb + nc4))*512 + lofs;
                bf16x8 bh2 = *(const bf16x8*)(DfBh + o);
                bf16x8 bl2 = *(const bf16x8*)(DfBl + o);
                #pragma unroll
                for(int cc=0;cc<4;cc++){
                    const int crow = cc*16 + r;
                    bf16x8 ah = *(const bf16x8*)&tl[sw2(crow, nc4*32 + g*8)];
                    bf16x8 al = *(const bf16x8*)&tl[sw2(crow, 128 + nc4*32 + g*8)];
                    acc2[cc][jj] = __builtin_amdgcn_mfma_f32_16x16x32_bf16(
                        ah, bh2, acc2[cc][jj], 0, 0, 0);
                    acc2[cc][jj] = __builtin_amdgcn_mfma_f32_16x16x32_bf16(
                        ah, bl2, acc2[cc][jj], 0, 0, 0);
                    acc2[cc][jj] = __builtin_amdgcn_mfma_f32_16x16x32_bf16(
                        al, bh2, acc2[cc][jj], 0, 0, 0);
                }
            }
        }
        // write part[ntile][b][c][j] as f16
        f16* P = part + ((size_t)blockIdx.x*32 + b)*8192;
        #pragma unroll
        for(int cc=0;cc<4;cc++)
            #pragma unroll
            for(int jj=0;jj<2;jj++)
                #pragma unroll
                for(int q=0;q<4;q++)
                    P[(size_t)(cc*16 + g*4 + q)*128 + (jt0+jj)*16 + r] =
                        (f16)acc2[cc][jj][q];
    } else {
        // ---- fused projection (l==3): out = p2 . gelu(p1 @ h + p1b) + p2b ----
        f32x4 acc3[8][2];
        #pragma unroll
        for(int jt=0;jt<8;jt++)
            #pragma unroll
            for(int ctn=0;ctn<2;ctn++) acc3[jt][ctn] = (f32x4){0.f,0.f,0.f,0.f};

        #pragma unroll
        for(int kc=0;kc<2;kc++){
            bf16x8 bh3[2], bl3[2];
            #pragma unroll
            for(int ctn=0;ctn<2;ctn++){
                const int prow = ctn*16 + r;
                bh3[ctn] = *(const bf16x8*)&tl[w*4096 + sw1(prow, kc*32 + g*8)];
                bl3[ctn] = *(const bf16x8*)&tl[w*4096 + sw1(prow, 64 + kc*32 + g*8)];
            }
            #pragma unroll
            for(int jt=0;jt<8;jt++){
                const size_t oa = ((size_t)(jt*2 + kc))*512 + lofs;
                bf16x8 ah = *(const bf16x8*)(p1h + oa);
                bf16x8 al = *(const bf16x8*)(p1l + oa);
                #pragma unroll
                for(int ctn=0;ctn<2;ctn++){
                    acc3[jt][ctn] = __builtin_amdgcn_mfma_f32_16x16x32_bf16(
                        ah, bh3[ctn], acc3[jt][ctn], 0, 0, 0);
                    acc3[jt][ctn] = __builtin_amdgcn_mfma_f32_16x16x32_bf16(
                        ah, bl3[ctn], acc3[jt][ctn], 0, 0, 0);
                    acc3[jt][ctn] = __builtin_amdgcn_mfma_f32_16x16x32_bf16(
                        al, bh3[ctn], acc3[jt][ctn], 0, 0, 0);
                }
            }
        }
        #pragma unroll
        for(int ctn=0;ctn<2;ctn++){
            float pd = 0.f;
            #pragma unroll
            for(int jt=0;jt<8;jt++)
                #pragma unroll
                for(int q=0;q<4;q++){
                    const int j = jt*16 + g*4 + q;
                    pd = fmaf(p2w[j], gelu_f(acc3[jt][ctn][q] + p1b[j]), pd);
                }
            pd += __shfl_xor(pd, 16, 64);
            pd += __shfl_xor(pd, 32, 64);
            if(g == 0)
                out[(size_t)b*NGRID + n0 + w*32 + ctn*16 + r] = pd + p2b[0];
        }
    }
}

// ==================== FP32 FALLBACK PATH ====================

__global__ void k_basis_fwd(float* __restrict__ D){
    int t = blockIdx.x * 256 + threadIdx.x;
    int n = t >> 7, j = t & 127, k = j & 63;
    int r = (k * n) & (NGRID - 1);
    float s, c;
    sincosf((float)r * 7.6699039394282061e-4f, &s, &c);
    D[t] = (j < 64) ? c : s;
}

__global__ void k_basis_inv(float* __restrict__ D){
    int t = blockIdx.x * 256 + threadIdx.x;
    int j = t >> 13, n = t & (NGRID - 1), k = j & 63;
    int r = (k * n) & (NGRID - 1);
    float s, c;
    sincosf((float)r * 7.6699039394282061e-4f, &s, &c);
    D[t] = (j < 64) ? c : s;
}

__global__ void k_lift(const float* __restrict__ x, const float* __restrict__ lw,
                       const float* __restrict__ lb, float* __restrict__ h){
    const int bc = blockIdx.x;
    const int b = bc >> 6, c = bc & 63;
    float A = lb[c];
    #pragma unroll
    for(int d = 0; d < 5; d++) A = fmaf(x[b*5 + d], lw[c*6 + d], A);
    const float v = lw[c*6 + 5];
    float* hp = h + (size_t)bc * NGRID;
    for(int n = threadIdx.x; n < NGRID; n += 256)
        hp[n] = fmaf((float)n * (1.0f/8191.0f), v, A);
}

__global__ __launch_bounds__(256) void k_dft(const float* __restrict__ h,
                                             const float* __restrict__ Dfwd,
                                             float* __restrict__ part,
                                             int chunk){
    const int m0 = blockIdx.x * 64;
    const int sp = blockIdx.y;
    const int kbase = sp * chunk;
    __shared__ float AsT[32][68];
    __shared__ float Bs[32][128];
    const int tid = threadIdx.x;
    const int tr = tid >> 4;
    const int tc = tid & 15;
    float acc[4][8];
    #pragma unroll
    for(int u=0;u<4;u++)
        #pragma unroll
        for(int v=0;v<8;v++) acc[u][v] = 0.f;

    for(int k0 = kbase; k0 < kbase + chunk; k0 += 32){
        {
            const int kk = tid & 31, r0 = tid >> 5;
            #pragma unroll
            for(int p=0;p<8;p++){
                const int row = r0 + p*8;
                AsT[kk][row] = h[(size_t)(m0+row)*NGRID + k0 + kk];
            }
        }
        {
            const int j = tid & 127, kb = tid >> 7;
            #pragma unroll
            for(int q=0;q<16;q++){
                const int kk = kb + q*2;
                Bs[kk][j] = Dfwd[(size_t)(k0+kk)*128 + j];
            }
        }
        __syncthreads();
        #pragma unroll
        for(int kk=0;kk<32;kk++){
            float a[4], bv[8];
            #pragma unroll
            for(int u=0;u<4;u++) a[u] = AsT[kk][tr*4+u];
            #pragma unroll
            for(int v=0;v<8;v++) bv[v] = Bs[kk][tc*8+v];
            #pragma unroll
            for(int u=0;u<4;u++)
                #pragma unroll
                for(int v=0;v<8;v++)
                    acc[u][v] = fmaf(a[u], bv[v], acc[u][v]);
        }
        __syncthreads();
    }
    float* P = part + (size_t)sp * (2048*128);
    #pragma unroll
    for(int u=0;u<4;u++){
        const int row = m0 + tr*4 + u;
        #pragma unroll
        for(int v=0;v<8;v++)
            P[(size_t)row*128 + tc*8 + v] = acc[u][v];
    }
}

__global__ __launch_bounds__(64) void k_mix(const float* __restrict__ Hf,
        const float* __restrict__ spW, const float* __restrict__ wcw,
        float* __restrict__ U, int l){
    const int bo = blockIdx.x;
    const int b = bo >> 6, o = bo & 63;
    const int k = threadIdx.x;
    const float* Hb = Hf + (size_t)b*64*128;
    const float* W = spW + (size_t)l*64*64*64*2;
    float ar = 0.f, ai = 0.f;
    for(int i=0;i<64;i++){
        const float hr = Hb[i*128 + k];
        const float hs = Hb[i*128 + 64 + k];
        const float* wp = W + (((size_t)i*64 + o)*64 + k)*2;
        const float wr = wp[0], wi = wp[1];
        ar = fmaf(hr, wr, fmaf(hs, wi, ar));
        ai = fmaf(hr, wi, fmaf(-hs, wr, ai));
    }
    const float ck = (k==0) ? (1.0f/8192.0f) : (2.0f/8192.0f);
    float* Ub = U + (size_t)bo * 192;
    Ub[k]       = ck * ar;
    Ub[64 + k]  = -ck * ai;
    Ub[128 + k] = wcw[(size_t)l*4096 + o*64 + k];
}

__global__ __launch_bounds__(256) void k_apply(const float* __restrict__ U,
                                               const float* __restrict__ Dinv,
                                               const float* __restrict__ wcb,
                                               float* __restrict__ h,
                                               int l){
    const int n0 = blockIdx.x * 128;
    const int b  = blockIdx.y;
    __shared__ float UsT[32][68];
    __shared__ float Vs[32][128];
    const int tid = threadIdx.x, tr = tid >> 4, tc = tid & 15;
    float acc[4][8];
    #pragma unroll
    for(int u=0;u<4;u++)
        #pragma unroll
        for(int v=0;v<8;v++) acc[u][v] = 0.f;
    const float* Ub = U + (size_t)b * (64*192);

    for(int k0=0;k0<192;k0+=32){
        {
            const int kk = tid & 31, r0 = tid >> 5;
            #pragma unroll
            for(int p=0;p<8;p++){
                const int o = r0 + p*8;
                UsT[kk][o] = Ub[o*192 + k0 + kk];
            }
        }
        {
            const int j = tid & 127, kb = tid >> 7;
            #pragma unroll
            for(int q=0;q<16;q++){
                const int kk = kb + q*2;
                const int kg = k0 + kk;
                const float* rp = (kg < 128) ? (Dinv + (size_t)kg*NGRID)
                                             : (h + ((size_t)b*64 + (kg-128))*NGRID);
                Vs[kk][j] = rp[n0 + j];
            }
        }
        __syncthreads();
        #pragma unroll
        for(int kk=0;kk<32;kk++){
            float a[4], bv[8];
            #pragma unroll
            for(int u=0;u<4;u++) a[u] = UsT[kk][tr*4+u];
            #pragma unroll
            for(int v=0;v<8;v++) bv[v] = Vs[kk][tc*8+v];
            #pragma unroll
            for(int u=0;u<4;u++)
                #pragma unroll
                for(int v=0;v<8;v++)
                    acc[u][v] = fmaf(a[u], bv[v], acc[u][v]);
        }
        __syncthreads();
    }
    #pragma unroll
    for(int u=0;u<4;u++){
        const int o = tr*4 + u;
        const float bias = wcb[l*64 + o];
        float* hp = h + ((size_t)b*64 + o)*NGRID + n0 + tc*8;
        #pragma unroll
        for(int v=0;v<8;v++)
            hp[v] = gelu_f(acc[u][v] + bias);
    }
}

__global__ __launch_bounds__(256) void k_proj(const float* __restrict__ h,
        const float* __restrict__ p1w, const float* __restrict__ p1b,
        const float* __restrict__ p2w, const float* __restrict__ p2b,
        float* __restrict__ out){
    const int n0 = blockIdx.x * 128;
    const int b  = blockIdx.y;
    __shared__ float Hs[64][128];
    __shared__ float P1T[64][128];
    const int tid = threadIdx.x, tr = tid >> 4, tc = tid & 15;
    {
        const int j = tid & 127, cb = tid >> 7;
        #pragma unroll
        for(int q=0;q<32;q++){
            const int c = cb + q*2;
            Hs[c][j] = h[((size_t)b*64 + c)*NGRID + n0 + j];
        }
    }
    {
        #pragma unroll
        for(int q=0;q<32;q++){
            const int e = q*256 + tid;
            const int j = e & 127, c = e >> 7;
            P1T[c][j] = p1w[j*64 + c];
        }
    }
    __syncthreads();
    float acc[8][8];
    #pragma unroll
    for(int u=0;u<8;u++)
        #pragma unroll
        for(int v=0;v<8;v++) acc[u][v] = 0.f;
    for(int c=0;c<64;c++){
        float pv[8], hv[8];
        #pragma unroll
        for(int u=0;u<8;u++) pv[u] = P1T[c][tr*8+u];
        #pragma unroll
        for(int v=0;v<8;v++) hv[v] = Hs[c][tc*8+v];
        #pragma unroll
        for(int u=0;u<8;u++)
            #pragma unroll
            for(int v=0;v<8;v++)
                acc[u][v] = fmaf(pv[u], hv[v], acc[u][v]);
    }
    float pd[8];
    #pragma unroll
    for(int v=0;v<8;v++) pd[v] = 0.f;
    #pragma unroll
    for(int u=0;u<8;u++){
        const int j = tr*8 + u;
        const float bj = p1b[j], wj = p2w[j];
        #pragma unroll
        for(int v=0;v<8;v++)
            pd[v] = fmaf(wj, gelu_f(acc[u][v] + bj), pd[v]);
    }
    __syncthreads();
    float* red = &P1T[0][0];
    #pragma unroll
    for(int v=0;v<8;v++) red[tr*128 + tc*8 + v] = pd[v];
    __syncthreads();
    if(tid < 128){
        float sY = p2b[0];
        #pragma unroll
        for(int r=0;r<16;r++) sY += red[r*128 + tid];
        out[(size_t)b*NGRID + n0 + tid] = sY;
    }
}

// ==================== LAUNCH ====================

extern "C" void kernel_launch(void* const* d_in, const int* in_sizes, int n_in,
                              void* d_out, int out_size, void* d_ws, size_t ws_size,
                              hipStream_t stream){
    const float* x   = (const float*)d_in[0];
    const float* lw  = (const float*)d_in[1];
    const float* lb  = (const float*)d_in[2];
    const float* spW = (const float*)d_in[3];
    const float* wcw = (const float*)d_in[4];
    const float* wcb = (const float*)d_in[5];
    const float* p1w = (const float*)d_in[6];
    const float* p1b = (const float*)d_in[7];
    const float* p2w = (const float*)d_in[8];
    const float* p2b = (const float*)d_in[9];
    float* out = (float*)d_out;

    const size_t N_H   = (size_t)32*64*NGRID;   // 16,777,216
    const size_t N_D   = (size_t)128*NGRID;     // 1,048,576
    const size_t N_U   = (size_t)32*64*192;     // 393,216
    const size_t N_P1  = 8192;
    // u16 arrays: hB(2) + Df(2) + Di(2) + U(2) + p1(2)
    const size_t ush_total = 2*N_H + 4*N_D + 2*N_U + 2*N_P1;
    // f32 Hf + 64-way f16 part
    const size_t need_new = ush_total*2 + (size_t)262144*4 + (size_t)64*262144*2;

    if(ws_size >= need_new){
        u16* W = (u16*)d_ws;
        u16* hBh = W; W += N_H;
        u16* hBl = W; W += N_H;
        u16* dfh = W; W += N_D;
        u16* dfl = W; W += N_D;
        u16* dih = W; W += N_D;
        u16* dil = W; W += N_D;
        u16* uh  = W; W += N_U;
        u16* ul  = W; W += N_U;
        u16* p1h = W; W += N_P1;
        u16* p1l = W; W += N_P1;
        float* Hf   = (float*)W;
        f16*  part  = (f16*)(Hf + 262144);

        k_prep_all<<<dim3(17440), dim3(256), 0, stream>>>(x, lw, lb, p1w,
                                                          dfh, dfl, dih, dil,
                                                          p1h, p1l, hBh, hBl, Hf);
        for(int l=0;l<4;l++){
            k_mix_m<<<dim3(512), dim3(256), 0, stream>>>(Hf, spW, wcw, uh, ul, l);
            k_apply_m<<<dim3(64, 32), dim3(256), 0, stream>>>(uh, ul, dih, dil, wcb,
                                                             dfh, dfl, hBh, hBl,
                                                             part, p1h, p1l,
                                                             p1b, p2w, p2b, out,
                                                             l, (l<3) ? 1 : 0);
            if(l < 3)
                k_reduce_h<<<dim3(256), dim3(256), 0, stream>>>(part, Hf, 64);
        }
        return;
    }

    // ---- fallback fp32 path ----
    float* ws  = (float*)d_ws;
    float* Dfwd = ws;
    float* Dinv = Dfwd + (size_t)NGRID*128;
    float* h    = Dinv + (size_t)128*NGRID;
    float* Hf   = h    + (size_t)32*64*NGRID;
    float* U    = Hf   + (size_t)2048*128;
    float* part = U    + (size_t)32*64*192;

    const size_t fixedf = (size_t)NGRID*128*2 + (size_t)32*64*NGRID
                        + (size_t)2048*128 + (size_t)32*64*192;
    int splits = 32;
    while(splits > 1 && (fixedf + (size_t)splits*2048*128)*sizeof(float) > ws_size)
        splits >>= 1;
    const int chunk = NGRID / splits;

    k_basis_fwd<<<dim3(4096), dim3(256), 0, stream>>>(Dfwd);
    k_basis_inv<<<dim3(4096), dim3(256), 0, stream>>>(Dinv);
    k_lift<<<dim3(2048), dim3(256), 0, stream>>>(x, lw, lb, h);
    for(int l=0;l<4;l++){
        k_dft<<<dim3(32, splits), dim3(256), 0, stream>>>(h, Dfwd, part, chunk);
        k_reduce<<<dim3(256), dim3(256), 0, stream>>>(part, Hf, splits);
        k_mix<<<dim3(2048), dim3(64), 0, stream>>>(Hf, spW, wcw, U, l);
        k_apply<<<dim3(64, 32), dim3(256), 0, stream>>>(U, Dinv, wcb, h, l);
    }
    k_proj<<<dim3(64, 32), dim3(256), 0, stream>>>(h, p1w, p1b, p2w, p2b, out);
}

// Round 30
// 322.147 us; speedup vs baseline: 1.0057x; 1.0019x over previous
//
#include <hip/hip_runtime.h>
#include <math.h>

#define NGRID 8192

typedef unsigned short u16;
typedef _Float16 f16;
typedef __attribute__((ext_vector_type(4))) float f32x4;
typedef __attribute__((ext_vector_type(4))) _Float16 f16x4;
typedef __attribute__((ext_vector_type(8))) short bf16x8;
typedef __attribute__((ext_vector_type(4))) short sh4;

// fast gelu: Abramowitz-Stegun 7.1.26 erf, |abs err| <= 1.5e-7
__device__ __forceinline__ float gelu_f(float x){
    float z = fabsf(x) * 0.70710678118654752f;
    float t = __builtin_amdgcn_rcpf(fmaf(0.3275911f, z, 1.0f));
    float p = fmaf(fmaf(fmaf(fmaf(1.061405429f, t, -1.453152027f), t,
                1.421413741f), t, -0.284496736f), t, 0.254829592f) * t;
    float er = 1.0f - p * __expf(-z*z);
    float s = (x >= 0.0f) ? er : -er;
    return 0.5f * x * (1.0f + s);
}

__device__ __forceinline__ u16 bf16_of(float x){
    union { float f; unsigned u; } v; v.f = x;
    unsigned r = v.u + 0x7fffu + ((v.u >> 16) & 1u);
    return (u16)(r >> 16);
}
__device__ __forceinline__ float f_of_bf16(u16 h){
    union { unsigned u; float f; } v; v.u = ((unsigned)h) << 16; return v.f;
}
__device__ __forceinline__ void split2(float x, u16* hi, u16* lo){
    u16 h = bf16_of(x);
    *hi = h;
    *lo = bf16_of(x - f_of_bf16(h));
}

// LDS swizzles (32KB views, XOR spreads banks; preserves 8B/16B alignment)
__device__ __forceinline__ int sw1(int row, int col){  // view1 [32][128] u16 per wave
    return row*128 + (col ^ ((row & 7) << 3));
}
__device__ __forceinline__ int sw2(int c, int col){    // view2 [64][256] u16
    return c*256 + (col ^ ((c & 7) << 3));
}

// Fragment-packed layouts: packed(row, k):
//   addr = TILE*512 + ((k>>3)&3)*128 + (row&15)*8 + (k&7)
// wave fragment load = lane*16B fully coalesced.

// ==================== MFMA PATH ====================

// merged prep: regions by blockIdx.x
//  [0,4096)      DfB basis      (1,048,576 elems)
//  [4096,8192)   DiB basis      (1,048,576)
//  [8192,8224)   p1 pack        (8,192)
//  [8224,16416)  hB lift        (2,097,152 threads x8)
//  [16416,17440) Hf0 closed form(262,144)
__global__ void k_prep_all(const float* __restrict__ x, const float* __restrict__ lw,
                           const float* __restrict__ lb, const float* __restrict__ p1w,
                           u16* __restrict__ dfh, u16* __restrict__ dfl,
                           u16* __restrict__ dih, u16* __restrict__ dil,
                           u16* __restrict__ p1h, u16* __restrict__ p1l,
                           u16* __restrict__ hBh, u16* __restrict__ hBl,
                           float* __restrict__ Hf){
    const int bid = blockIdx.x;
    if(bid < 4096){
        int t = bid * 256 + threadIdx.x;
        int s = t & 7, r = (t >> 3) & 15, g = (t >> 7) & 3;
        int nc = (t >> 9) & 255, jt = t >> 17;
        int j = jt * 16 + r, n = nc * 32 + g * 8 + s, k = j & 63;
        int rr = (k * n) & (NGRID - 1);
        float sn, cs;
        sincosf((float)rr * 7.6699039394282061e-4f, &sn, &cs);
        float val = (j < 64) ? cs : sn;
        u16 h, l; split2(val, &h, &l);
        dfh[t] = h; dfl[t] = l;
    } else if(bid < 8192){
        int t = (bid - 4096) * 256 + threadIdx.x;
        int s = t & 7, r = (t >> 3) & 15, g = (t >> 7) & 3;
        int kt = (t >> 9) & 3, nt = t >> 11;
        int n = nt * 16 + r, k = kt * 32 + g * 8 + s, kk = k & 63;
        int rr = (kk * n) & (NGRID - 1);
        float sn, cs;
        sincosf((float)rr * 7.6699039394282061e-4f, &sn, &cs);
        float val = (k < 64) ? cs : sn;
        u16 h, l; split2(val, &h, &l);
        dih[t] = h; dil[t] = l;
    } else if(bid < 8224){
        int t = (bid - 8192) * 256 + threadIdx.x;
        int s = t & 7, r = (t >> 3) & 15, g = (t >> 7) & 3;
        int kt = (t >> 9) & 1, jt = t >> 10;
        int j = jt * 16 + r, c = kt * 32 + g * 8 + s;
        u16 h, l; split2(p1w[j * 64 + c], &h, &l);
        p1h[t] = h; p1l[t] = l;
    } else if(bid < 16416){
        int T = (bid - 8224) * 256 + threadIdx.x;
        int r = T & 15, g = (T >> 4) & 3;
        int kt = (T >> 6) & 1, nt = (T >> 7) & 511, b = T >> 16;
        int n = nt * 16 + r;
        int cbase = kt * 32 + g * 8;
        const float gr = (float)n * (1.0f/8191.0f);
        bf16x8 vh, vl;
        #pragma unroll
        for(int s = 0; s < 8; s++){
            const int c = cbase + s;
            float A = lb[c];
            #pragma unroll
            for(int d = 0; d < 5; d++) A = fmaf(x[b*5 + d], lw[c*6 + d], A);
            float val = fmaf(gr, lw[c*6 + 5], A);
            u16 h, l; split2(val, &h, &l);
            vh[s] = (short)h; vl[s] = (short)l;
        }
        *(bf16x8*)(hBh + (size_t)T*8) = vh;
        *(bf16x8*)(hBl + (size_t)T*8) = vl;
    } else {
        int t = (bid - 16416) * 256 + threadIdx.x;
        int j = t & 127, c = (t >> 7) & 63, b = t >> 13;
        float A = lb[c];
        #pragma unroll
        for(int d = 0; d < 5; d++) A = fmaf(x[b*5 + d], lw[c*6 + d], A);
        const float v = lw[c*6 + 5];
        float val;
        if(j < 64){
            val = (j == 0) ? fmaf(8192.f, A, 4096.f * v)
                           : (-4096.f/8191.f) * v;
        } else {
            int jj = j - 64;
            if(jj == 0) val = 0.f;
            else {
                float sn, cs;
                sincosf((float)jj * 3.8349519697141029e-4f, &sn, &cs);  // pi/8192
                val = (-4096.f/8191.f) * v * (cs / sn);
            }
        }
        Hf[t] = val;
    }
}

// f16 reduce: 65536 threads x f16x4 -> f32x4
__global__ void k_reduce_h(const f16* __restrict__ part, float* __restrict__ Hf, int splits){
    const int t = blockIdx.x*256 + threadIdx.x;   // 65536
    f32x4 s = (f32x4){0.f,0.f,0.f,0.f};
    for(int i=0;i<splits;i++){
        f16x4 v = *(const f16x4*)(part + (size_t)i*(2048*128) + (size_t)t*4);
        s[0] += (float)v[0];
        s[1] += (float)v[1];
        s[2] += (float)v[2];
        s[3] += (float)v[3];
    }
    *(f32x4*)(Hf + (size_t)t*4) = s;
}

// f32 reduce (fallback path)
__global__ void k_reduce(const float* __restrict__ part, float* __restrict__ Hf, int splits){
    const int t = blockIdx.x*256 + threadIdx.x;   // 65536
    f32x4 s = (f32x4){0.f,0.f,0.f,0.f};
    for(int i=0;i<splits;i++){
        f32x4 v = *(const f32x4*)(part + (size_t)i*(2048*128) + (size_t)t*4);
        s += v;
    }
    *(f32x4*)(Hf + (size_t)t*4) = s;
}

// mode mix: Hf[b] staged in LDS, TLP-preserving grid.
// grid (32 b x 16 o-groups) = 512 blocks, block 256 = 4 waves;
// wave = one o (o = og*4 + w), lane = k. 2048 waves total.
__global__ __launch_bounds__(256) void k_mix_m(const float* __restrict__ Hf,
        const float* __restrict__ spW, const float* __restrict__ wcw,
        u16* __restrict__ Uhi, u16* __restrict__ Ulo, int l){
    const int b  = blockIdx.x >> 4;
    const int og = blockIdx.x & 15;
    const int tid = threadIdx.x;
    const int w = tid >> 6, k = tid & 63;
    const int o = og*4 + w;
    __shared__ float hf[8192];               // 32 KB: Hf[b][i][128]
    {
        const f32x4* src = (const f32x4*)(Hf + (size_t)b*8192);
        f32x4* dst = (f32x4*)hf;
        #pragma unroll
        for(int q=0;q<8;q++) dst[q*256 + tid] = src[q*256 + tid];
    }
    __syncthreads();

    const float* W = spW + (size_t)l*524288;
    float ar = 0.f, ai = 0.f;
    for(int i=0;i<64;i++){
        const float hr = hf[i*128 + k];
        const float hs = hf[i*128 + 64 + k];
        const float* wp = W + (((size_t)i*64 + o)*64 + k)*2;
        const float wr = wp[0], wi = wp[1];
        ar = fmaf(hr, wr, fmaf(hs, wi, ar));
        ai = fmaf(hr, wi, fmaf(-hs, wr, ai));
    }
    const float ck = (k==0) ? (1.0f/8192.0f) : (2.0f/8192.0f);
    const size_t tbase = (size_t)(b*4 + (o>>4))*6;
    const size_t sub = (size_t)((k>>3)&3)*128 + (size_t)(o&15)*8 + (size_t)(k&7);
    u16 h, lo;
    split2(ck * ar, &h, &lo);
    Uhi[(tbase + (k>>5))*512 + sub] = h;      Ulo[(tbase + (k>>5))*512 + sub] = lo;
    split2(-ck * ai, &h, &lo);
    Uhi[(tbase + 2 + (k>>5))*512 + sub] = h;  Ulo[(tbase + 2 + (k>>5))*512 + sub] = lo;
    split2(wcw[(size_t)l*4096 + o*64 + k], &h, &lo);
    Uhi[(tbase + 4 + (k>>5))*512 + sub] = h;  Ulo[(tbase + 4 + (k>>5))*512 + sub] = lo;
}

// fused inv-DFT + 1x1 conv + gelu + forward-DFT partials (l<3) or proj (l==3)
// grid (64 n-tiles of 128, 32 b), block 256 = 4 waves; wave tile 64(o) x 32(n)
// 32 KB LDS (XOR-swizzled views); B-stream software-prefetched (reg dbuf)
__global__ __launch_bounds__(256) void k_apply_m(const u16* __restrict__ Uhi,
        const u16* __restrict__ Ulo, const u16* __restrict__ Dihi,
        const u16* __restrict__ Dilo, const float* __restrict__ wcb,
        const u16* __restrict__ DfBh, const u16* __restrict__ DfBl,
        u16* __restrict__ hB_hi, u16* __restrict__ hB_lo,
        f16* __restrict__ part,
        const u16* __restrict__ p1h, const u16* __restrict__ p1l,
        const float* __restrict__ p1b, const float* __restrict__ p2w,
        const float* __restrict__ p2b, float* __restrict__ out,
        int l, int do_dft){
    const int n0 = blockIdx.x * 128;
    const int b  = blockIdx.y;
    const int tid = threadIdx.x, w = tid >> 6, lane = tid & 63;
    const int r = lane & 15, g = lane >> 4;
    const int lofs = g * 128 + r * 8;
    const int nw = n0 + w*32;
    __shared__ __align__(16) u16 tl[16384];   // 32,768 B
    // view 1 (transpose): per wave [32][128] u16, sw1: hi cols 0..63, lo 64..127
    // view 2 (DFT stage): [64][256] u16, sw2: hi cols 0..127, lo 128..255
    f32x4 acc[4][2];
    #pragma unroll
    for(int i=0;i<4;i++)
        #pragma unroll
        for(int j=0;j<2;j++) acc[i][j] = (f32x4){0.f,0.f,0.f,0.f};

    // kt 0..3: B = Dinv; kt 4..5: B = hB. B-stream prefetched one kt ahead.
    bf16x8 pbh[2], pbl[2];
    #pragma unroll
    for(int ct=0;ct<2;ct++){
        const int nt = (nw >> 4) + ct;
        const size_t o = ((size_t)(nt*4))*512 + lofs;
        pbh[ct] = *(const bf16x8*)(Dihi + o);
        pbl[ct] = *(const bf16x8*)(Dilo + o);
    }
    #pragma unroll
    for(int kt=0;kt<6;kt++){
        bf16x8 bh[2], bl[2];
        #pragma unroll
        for(int ct=0;ct<2;ct++){ bh[ct] = pbh[ct]; bl[ct] = pbl[ct]; }
        if(kt < 5){
            const int k2 = kt + 1;
            #pragma unroll
            for(int ct=0;ct<2;ct++){
                const int nt = (nw >> 4) + ct;
                if(k2 < 4){
                    const size_t o = ((size_t)(nt*4 + k2))*512 + lofs;
                    pbh[ct] = *(const bf16x8*)(Dihi + o);
                    pbl[ct] = *(const bf16x8*)(Dilo + o);
                } else {
                    const size_t o = ((size_t)((b*512 + nt)*2 + (k2-4)))*512 + lofs;
                    pbh[ct] = *(const bf16x8*)(hB_hi + o);
                    pbl[ct] = *(const bf16x8*)(hB_lo + o);
                }
            }
        }
        #pragma unroll
        for(int ct=0;ct<2;ct++){
            #pragma unroll
            for(int rt=0;rt<4;rt++){
                const size_t o = ((size_t)((b*4 + rt)*6 + kt))*512 + lofs;
                bf16x8 ah = *(const bf16x8*)(Uhi + o);
                bf16x8 al = *(const bf16x8*)(Ulo + o);
                acc[rt][ct] = __builtin_amdgcn_mfma_f32_16x16x32_bf16(
                    ah, bh[ct], acc[rt][ct], 0, 0, 0);
                acc[rt][ct] = __builtin_amdgcn_mfma_f32_16x16x32_bf16(
                    ah, bl[ct], acc[rt][ct], 0, 0, 0);
                acc[rt][ct] = __builtin_amdgcn_mfma_f32_16x16x32_bf16(
                    al, bh[ct], acc[rt][ct], 0, 0, 0);
            }
        }
    }
    // epilogue: bias + gelu
    #pragma unroll
    for(int rt=0;rt<4;rt++)
        #pragma unroll
        for(int q=0;q<4;q++){
            const int o = rt*16 + g*4 + q;
            const float bias = wcb[l*64 + o];
            #pragma unroll
            for(int ct=0;ct<2;ct++)
                acc[rt][ct][q] = gelu_f(acc[rt][ct][q] + bias);
        }

    // ---- hB single-pass: view1 per wave, swizzled ----
    sh4 svh[4][2], svl[4][2];
    #pragma unroll
    for(int rt=0;rt<4;rt++)
        #pragma unroll
        for(int ct=0;ct<2;ct++){
            sh4 vh_, vl_;
            #pragma unroll
            for(int q=0;q<4;q++){
                float val = acc[rt][ct][q];
                u16 hh = bf16_of(val);
                vh_[q] = (short)hh;
                vl_[q] = (short)bf16_of(val - f_of_bf16(hh));
            }
            svh[rt][ct] = vh_;
            svl[rt][ct] = vl_;
            const int row = ct*16 + r, col = rt*16 + g*4;
            *(sh4*)&tl[w*4096 + sw1(row, col)]      = vh_;
            *(sh4*)&tl[w*4096 + sw1(row, 64 + col)] = vl_;
        }
    __syncthreads();
    if(do_dft){
        // global hB store (only needed when a later layer reads it)
        const int row_local = tid >> 1, half = tid & 1;
        const int ww = row_local >> 5, nn = row_local & 31;
        const int n = n0 + row_local;
        const int nt = n >> 4, rr = n & 15;
        const size_t dof = ((size_t)((b*512 + nt)*2 + half))*512 + rr*8;
        #pragma unroll
        for(int s=0;s<4;s++){
            bf16x8 v = *(const bf16x8*)&tl[ww*4096 + sw1(nn, half*32 + s*8)];
            *(bf16x8*)(hB_hi + dof + s*128) = v;
        }
        #pragma unroll
        for(int s=0;s<4;s++){
            bf16x8 v = *(const bf16x8*)&tl[ww*4096 + sw1(nn, 64 + half*32 + s*8)];
            *(bf16x8*)(hB_lo + dof + s*128) = v;
        }
    }
    __syncthreads();

    if(do_dft){
        // ---- fused forward DFT: restage hi+lo into view2 from registers ----
        #pragma unroll
        for(int rt=0;rt<4;rt++)
            #pragma unroll
            for(int ct=0;ct<2;ct++)
                #pragma unroll
                for(int q=0;q<4;q++){
                    const int o0 = rt*16 + g*4 + q;
                    const int nl = w*32 + ct*16 + r;
                    tl[sw2(o0, nl)]       = (u16)svh[rt][ct][q];
                    tl[sw2(o0, 128 + nl)] = (u16)svl[rt][ct][q];
                }
        __syncthreads();

        f32x4 acc2[4][2];
        #pragma unroll
        for(int cc=0;cc<4;cc++)
            #pragma unroll
            for(int jj=0;jj<2;jj++) acc2[cc][jj] = (f32x4){0.f,0.f,0.f,0.f};
        const int jt0 = w*2;
        const int ncb = n0 >> 5;

        // DfB stream prefetched one step ahead (8 steps: nc4*2+jj)
        bf16x8 pbh2, pbl2;
        {
            const size_t o = ((size_t)(jt0*256 + ncb))*512 + lofs;
            pbh2 = *(const bf16x8*)(DfBh + o);
            pbl2 = *(const bf16x8*)(DfBl + o);
        }
        #pragma unroll
        for(int nc4=0;nc4<4;nc4++){
            #pragma unroll
            for(int jj=0;jj<2;jj++){
                bf16x8 bh2 = pbh2, bl2 = pbl2;
                const int idx = nc4*2 + jj;
                if(idx < 7){
                    const int nidx = idx + 1;
                    const int nnc4 = nidx >> 1, njj = nidx & 1;
                    const size_t o = ((size_t)((jt0+njj)*256 + ncb + nnc4))*512 + lofs;
                    pbh2 = *(const bf16x8*)(DfBh + o);
                    pbl2 = *(const bf16x8*)(DfBl + o);
                }
                #pragma unroll
                for(int cc=0;cc<4;cc++){
                    const int crow = cc*16 + r;
                    bf16x8 ah = *(const bf16x8*)&tl[sw2(crow, nc4*32 + g*8)];
                    bf16x8 al = *(const bf16x8*)&tl[sw2(crow, 128 + nc4*32 + g*8)];
                    acc2[cc][jj] = __builtin_amdgcn_mfma_f32_16x16x32_bf16(
                        ah, bh2, acc2[cc][jj], 0, 0, 0);
                    acc2[cc][jj] = __builtin_amdgcn_mfma_f32_16x16x32_bf16(
                        ah, bl2, acc2[cc][jj], 0, 0, 0);
                    acc2[cc][jj] = __builtin_amdgcn_mfma_f32_16x16x32_bf16(
                        al, bh2, acc2[cc][jj], 0, 0, 0);
                }
            }
        }
        // write part[ntile][b][c][j] as f16
        f16* P = part + ((size_t)blockIdx.x*32 + b)*8192;
        #pragma unroll
        for(int cc=0;cc<4;cc++)
            #pragma unroll
            for(int jj=0;jj<2;jj++)
                #pragma unroll
                for(int q=0;q<4;q++)
                    P[(size_t)(cc*16 + g*4 + q)*128 + (jt0+jj)*16 + r] =
                        (f16)acc2[cc][jj][q];
    } else {
        // ---- fused projection (l==3): out = p2 . gelu(p1 @ h + p1b) + p2b ----
        f32x4 acc3[8][2];
        #pragma unroll
        for(int jt=0;jt<8;jt++)
            #pragma unroll
            for(int ctn=0;ctn<2;ctn++) acc3[jt][ctn] = (f32x4){0.f,0.f,0.f,0.f};

        #pragma unroll
        for(int kc=0;kc<2;kc++){
            bf16x8 bh3[2], bl3[2];
            #pragma unroll
            for(int ctn=0;ctn<2;ctn++){
                const int prow = ctn*16 + r;
                bh3[ctn] = *(const bf16x8*)&tl[w*4096 + sw1(prow, kc*32 + g*8)];
                bl3[ctn] = *(const bf16x8*)&tl[w*4096 + sw1(prow, 64 + kc*32 + g*8)];
            }
            #pragma unroll
            for(int jt=0;jt<8;jt++){
                const size_t oa = ((size_t)(jt*2 + kc))*512 + lofs;
                bf16x8 ah = *(const bf16x8*)(p1h + oa);
                bf16x8 al = *(const bf16x8*)(p1l + oa);
                #pragma unroll
                for(int ctn=0;ctn<2;ctn++){
                    acc3[jt][ctn] = __builtin_amdgcn_mfma_f32_16x16x32_bf16(
                        ah, bh3[ctn], acc3[jt][ctn], 0, 0, 0);
                    acc3[jt][ctn] = __builtin_amdgcn_mfma_f32_16x16x32_bf16(
                        ah, bl3[ctn], acc3[jt][ctn], 0, 0, 0);
                    acc3[jt][ctn] = __builtin_amdgcn_mfma_f32_16x16x32_bf16(
                        al, bh3[ctn], acc3[jt][ctn], 0, 0, 0);
                }
            }
        }
        #pragma unroll
        for(int ctn=0;ctn<2;ctn++){
            float pd = 0.f;
            #pragma unroll
            for(int jt=0;jt<8;jt++)
                #pragma unroll
                for(int q=0;q<4;q++){
                    const int j = jt*16 + g*4 + q;
                    pd = fmaf(p2w[j], gelu_f(acc3[jt][ctn][q] + p1b[j]), pd);
                }
            pd += __shfl_xor(pd, 16, 64);
            pd += __shfl_xor(pd, 32, 64);
            if(g == 0)
                out[(size_t)b*NGRID + n0 + w*32 + ctn*16 + r] = pd + p2b[0];
        }
    }
}

// ==================== FP32 FALLBACK PATH ====================

__global__ void k_basis_fwd(float* __restrict__ D){
    int t = blockIdx.x * 256 + threadIdx.x;
    int n = t >> 7, j = t & 127, k = j & 63;
    int r = (k * n) & (NGRID - 1);
    float s, c;
    sincosf((float)r * 7.6699039394282061e-4f, &s, &c);
    D[t] = (j < 64) ? c : s;
}

__global__ void k_basis_inv(float* __restrict__ D){
    int t = blockIdx.x * 256 + threadIdx.x;
    int j = t >> 13, n = t & (NGRID - 1), k = j & 63;
    int r = (k * n) & (NGRID - 1);
    float s, c;
    sincosf((float)r * 7.6699039394282061e-4f, &s, &c);
    D[t] = (j < 64) ? c : s;
}

__global__ void k_lift(const float* __restrict__ x, const float* __restrict__ lw,
                       const float* __restrict__ lb, float* __restrict__ h){
    const int bc = blockIdx.x;
    const int b = bc >> 6, c = bc & 63;
    float A = lb[c];
    #pragma unroll
    for(int d = 0; d < 5; d++) A = fmaf(x[b*5 + d], lw[c*6 + d], A);
    const float v = lw[c*6 + 5];
    float* hp = h + (size_t)bc * NGRID;
    for(int n = threadIdx.x; n < NGRID; n += 256)
        hp[n] = fmaf((float)n * (1.0f/8191.0f), v, A);
}

__global__ __launch_bounds__(256) void k_dft(const float* __restrict__ h,
                                             const float* __restrict__ Dfwd,
                                             float* __restrict__ part,
                                             int chunk){
    const int m0 = blockIdx.x * 64;
    const int sp = blockIdx.y;
    const int kbase = sp * chunk;
    __shared__ float AsT[32][68];
    __shared__ float Bs[32][128];
    const int tid = threadIdx.x;
    const int tr = tid >> 4;
    const int tc = tid & 15;
    float acc[4][8];
    #pragma unroll
    for(int u=0;u<4;u++)
        #pragma unroll
        for(int v=0;v<8;v++) acc[u][v] = 0.f;

    for(int k0 = kbase; k0 < kbase + chunk; k0 += 32){
        {
            const int kk = tid & 31, r0 = tid >> 5;
            #pragma unroll
            for(int p=0;p<8;p++){
                const int row = r0 + p*8;
                AsT[kk][row] = h[(size_t)(m0+row)*NGRID + k0 + kk];
            }
        }
        {
            const int j = tid & 127, kb = tid >> 7;
            #pragma unroll
            for(int q=0;q<16;q++){
                const int kk = kb + q*2;
                Bs[kk][j] = Dfwd[(size_t)(k0+kk)*128 + j];
            }
        }
        __syncthreads();
        #pragma unroll
        for(int kk=0;kk<32;kk++){
            float a[4], bv[8];
            #pragma unroll
            for(int u=0;u<4;u++) a[u] = AsT[kk][tr*4+u];
            #pragma unroll
            for(int v=0;v<8;v++) bv[v] = Bs[kk][tc*8+v];
            #pragma unroll
            for(int u=0;u<4;u++)
                #pragma unroll
                for(int v=0;v<8;v++)
                    acc[u][v] = fmaf(a[u], bv[v], acc[u][v]);
        }
        __syncthreads();
    }
    float* P = part + (size_t)sp * (2048*128);
    #pragma unroll
    for(int u=0;u<4;u++){
        const int row = m0 + tr*4 + u;
        #pragma unroll
        for(int v=0;v<8;v++)
            P[(size_t)row*128 + tc*8 + v] = acc[u][v];
    }
}

__global__ __launch_bounds__(64) void k_mix(const float* __restrict__ Hf,
        const float* __restrict__ spW, const float* __restrict__ wcw,
        float* __restrict__ U, int l){
    const int bo = blockIdx.x;
    const int b = bo >> 6, o = bo & 63;
    const int k = threadIdx.x;
    const float* Hb = Hf + (size_t)b*64*128;
    const float* W = spW + (size_t)l*64*64*64*2;
    float ar = 0.f, ai = 0.f;
    for(int i=0;i<64;i++){
        const float hr = Hb[i*128 + k];
        const float hs = Hb[i*128 + 64 + k];
        const float* wp = W + (((size_t)i*64 + o)*64 + k)*2;
        const float wr = wp[0], wi = wp[1];
        ar = fmaf(hr, wr, fmaf(hs, wi, ar));
        ai = fmaf(hr, wi, fmaf(-hs, wr, ai));
    }
    const float ck = (k==0) ? (1.0f/8192.0f) : (2.0f/8192.0f);
    float* Ub = U + (size_t)bo * 192;
    Ub[k]       = ck * ar;
    Ub[64 + k]  = -ck * ai;
    Ub[128 + k] = wcw[(size_t)l*4096 + o*64 + k];
}

__global__ __launch_bounds__(256) void k_apply(const float* __restrict__ U,
                                               const float* __restrict__ Dinv,
                                               const float* __restrict__ wcb,
                                               float* __restrict__ h,
                                               int l){
    const int n0 = blockIdx.x * 128;
    const int b  = blockIdx.y;
    __shared__ float UsT[32][68];
    __shared__ float Vs[32][128];
    const int tid = threadIdx.x, tr = tid >> 4, tc = tid & 15;
    float acc[4][8];
    #pragma unroll
    for(int u=0;u<4;u++)
        #pragma unroll
        for(int v=0;v<8;v++) acc[u][v] = 0.f;
    const float* Ub = U + (size_t)b * (64*192);

    for(int k0=0;k0<192;k0+=32){
        {
            const int kk = tid & 31, r0 = tid >> 5;
            #pragma unroll
            for(int p=0;p<8;p++){
                const int o = r0 + p*8;
                UsT[kk][o] = Ub[o*192 + k0 + kk];
            }
        }
        {
            const int j = tid & 127, kb = tid >> 7;
            #pragma unroll
            for(int q=0;q<16;q++){
                const int kk = kb + q*2;
                const int kg = k0 + kk;
                const float* rp = (kg < 128) ? (Dinv + (size_t)kg*NGRID)
                                             : (h + ((size_t)b*64 + (kg-128))*NGRID);
                Vs[kk][j] = rp[n0 + j];
            }
        }
        __syncthreads();
        #pragma unroll
        for(int kk=0;kk<32;kk++){
            float a[4], bv[8];
            #pragma unroll
            for(int u=0;u<4;u++) a[u] = UsT[kk][tr*4+u];
            #pragma unroll
            for(int v=0;v<8;v++) bv[v] = Vs[kk][tc*8+v];
            #pragma unroll
            for(int u=0;u<4;u++)
                #pragma unroll
                for(int v=0;v<8;v++)
                    acc[u][v] = fmaf(a[u], bv[v], acc[u][v]);
        }
        __syncthreads();
    }
    #pragma unroll
    for(int u=0;u<4;u++){
        const int o = tr*4 + u;
        const float bias = wcb[l*64 + o];
        float* hp = h + ((size_t)b*64 + o)*NGRID + n0 + tc*8;
        #pragma unroll
        for(int v=0;v<8;v++)
            hp[v] = gelu_f(acc[u][v] + bias);
    }
}

__global__ __launch_bounds__(256) void k_proj(const float* __restrict__ h,
        const float* __restrict__ p1w, const float* __restrict__ p1b,
        const float* __restrict__ p2w, const float* __restrict__ p2b,
        float* __restrict__ out){
    const int n0 = blockIdx.x * 128;
    const int b  = blockIdx.y;
    __shared__ float Hs[64][128];
    __shared__ float P1T[64][128];
    const int tid = threadIdx.x, tr = tid >> 4, tc = tid & 15;
    {
        const int j = tid & 127, cb = tid >> 7;
        #pragma unroll
        for(int q=0;q<32;q++){
            const int c = cb + q*2;
            Hs[c][j] = h[((size_t)b*64 + c)*NGRID + n0 + j];
        }
    }
    {
        #pragma unroll
        for(int q=0;q<32;q++){
            const int e = q*256 + tid;
            const int j = e & 127, c = e >> 7;
            P1T[c][j] = p1w[j*64 + c];
        }
    }
    __syncthreads();
    float acc[8][8];
    #pragma unroll
    for(int u=0;u<8;u++)
        #pragma unroll
        for(int v=0;v<8;v++) acc[u][v] = 0.f;
    for(int c=0;c<64;c++){
        float pv[8], hv[8];
        #pragma unroll
        for(int u=0;u<8;u++) pv[u] = P1T[c][tr*8+u];
        #pragma unroll
        for(int v=0;v<8;v++) hv[v] = Hs[c][tc*8+v];
        #pragma unroll
        for(int u=0;u<8;u++)
            #pragma unroll
            for(int v=0;v<8;v++)
                acc[u][v] = fmaf(pv[u], hv[v], acc[u][v]);
    }
    float pd[8];
    #pragma unroll
    for(int v=0;v<8;v++) pd[v] = 0.f;
    #pragma unroll
    for(int u=0;u<8;u++){
        const int j = tr*8 + u;
        const float bj = p1b[j], wj = p2w[j];
        #pragma unroll
        for(int v=0;v<8;v++)
            pd[v] = fmaf(wj, gelu_f(acc[u][v] + bj), pd[v]);
    }
    __syncthreads();
    float* red = &P1T[0][0];
    #pragma unroll
    for(int v=0;v<8;v++) red[tr*128 + tc*8 + v] = pd[v];
    __syncthreads();
    if(tid < 128){
        float sY = p2b[0];
        #pragma unroll
        for(int r=0;r<16;r++) sY += red[r*128 + tid];
        out[(size_t)b*NGRID + n0 + tid] = sY;
    }
}

// ==================== LAUNCH ====================

extern "C" void kernel_launch(void* const* d_in, const int* in_sizes, int n_in,
                              void* d_out, int out_size, void* d_ws, size_t ws_size,
                              hipStream_t stream){
    const float* x   = (const float*)d_in[0];
    const float* lw  = (const float*)d_in[1];
    const float* lb  = (const float*)d_in[2];
    const float* spW = (const float*)d_in[3];
    const float* wcw = (const float*)d_in[4];
    const float* wcb = (const float*)d_in[5];
    const float* p1w = (const float*)d_in[6];
    const float* p1b = (const float*)d_in[7];
    const float* p2w = (const float*)d_in[8];
    const float* p2b = (const float*)d_in[9];
    float* out = (float*)d_out;

    const size_t N_H   = (size_t)32*64*NGRID;   // 16,777,216
    const size_t N_D   = (size_t)128*NGRID;     // 1,048,576
    const size_t N_U   = (size_t)32*64*192;     // 393,216
    const size_t N_P1  = 8192;
    // u16 arrays: hB(2) + Df(2) + Di(2) + U(2) + p1(2)
    const size_t ush_total = 2*N_H + 4*N_D + 2*N_U + 2*N_P1;
    // f32 Hf + 64-way f16 part
    const size_t need_new = ush_total*2 + (size_t)262144*4 + (size_t)64*262144*2;

    if(ws_size >= need_new){
        u16* W = (u16*)d_ws;
        u16* hBh = W; W += N_H;
        u16* hBl = W; W += N_H;
        u16* dfh = W; W += N_D;
        u16* dfl = W; W += N_D;
        u16* dih = W; W += N_D;
        u16* dil = W; W += N_D;
        u16* uh  = W; W += N_U;
        u16* ul  = W; W += N_U;
        u16* p1h = W; W += N_P1;
        u16* p1l = W; W += N_P1;
        float* Hf   = (float*)W;
        f16*  part  = (f16*)(Hf + 262144);

        k_prep_all<<<dim3(17440), dim3(256), 0, stream>>>(x, lw, lb, p1w,
                                                          dfh, dfl, dih, dil,
                                                          p1h, p1l, hBh, hBl, Hf);
        for(int l=0;l<4;l++){
            k_mix_m<<<dim3(512), dim3(256), 0, stream>>>(Hf, spW, wcw, uh, ul, l);
            k_apply_m<<<dim3(64, 32), dim3(256), 0, stream>>>(uh, ul, dih, dil, wcb,
                                                             dfh, dfl, hBh, hBl,
                                                             part, p1h, p1l,
                                                             p1b, p2w, p2b, out,
                                                             l, (l<3) ? 1 : 0);
            if(l < 3)
                k_reduce_h<<<dim3(256), dim3(256), 0, stream>>>(part, Hf, 64);
        }
        return;
    }

    // ---- fallback fp32 path ----
    float* ws  = (float*)d_ws;
    float* Dfwd = ws;
    float* Dinv = Dfwd + (size_t)NGRID*128;
    float* h    = Dinv + (size_t)128*NGRID;
    float* Hf   = h    + (size_t)32*64*NGRID;
    float* U    = Hf   + (size_t)2048*128;
    float* part = U    + (size_t)32*64*192;

    const size_t fixedf = (size_t)NGRID*128*2 + (size_t)32*64*NGRID
                        + (size_t)2048*128 + (size_t)32*64*192;
    int splits = 32;
    while(splits > 1 && (fixedf + (size_t)splits*2048*128)*sizeof(float) > ws_size)
        splits >>= 1;
    const int chunk = NGRID / splits;

    k_basis_fwd<<<dim3(4096), dim3(256), 0, stream>>>(Dfwd);
    k_basis_inv<<<dim3(4096), dim3(256), 0, stream>>>(Dinv);
    k_lift<<<dim3(2048), dim3(256), 0, stream>>>(x, lw, lb, h);
    for(int l=0;l<4;l++){
        k_dft<<<dim3(32, splits), dim3(256), 0, stream>>>(h, Dfwd, part, chunk);
        k_reduce<<<dim3(256), dim3(256), 0, stream>>>(part, Hf, splits);
        k_mix<<<dim3(2048), dim3(64), 0, stream>>>(Hf, spW, wcw, U, l);
        k_apply<<<dim3(64, 32), dim3(256), 0, stream>>>(U, Dinv, wcb, h, l);
    }
    k_proj<<<dim3(64, 32), dim3(256), 0, stream>>>(h, p1w, p1b, p2w, p2b, out);
}